// Round 1
// baseline (951.439 us; speedup 1.0000x reference)
//
#include <hip/hip_runtime.h>
#include <hip/hip_bf16.h>

#define T_WIN 336
#define T_OUT 48
#define T_S   168
#define BM    128
#define HC    32

// ---------------- colsum of W1 ----------------
__global__ __launch_bounds__(64) void cs_kernel(const float* __restrict__ W1,
                                                float* __restrict__ cs) {
    int k = blockIdx.x * 64 + threadIdx.x;
    if (k < T_WIN) {
        float s = 0.f;
        for (int j = 0; j < T_WIN; ++j) s += W1[j * T_WIN + k];
        cs[k] = s;
    }
}

// ---------------- sequential ES scan, chunk-parallel over the S=168 lag ----------------
// One wave. Lane l owns elements j=3l..3l+2 of each 168-chunk (lanes 0..55 active).
// level recurrence: lv = q*lv + a*x/w  (q=1-a), w known one chunk ahead:
// w[t+168] = g*x[t]/level[t] + (1-g)*w[t]  -- computed by the SAME lane that needs it next chunk.
__global__ __launch_bounds__(64) void scan_kernel(
    const float* __restrict__ x, const float* __restrict__ lvl_coef,
    const float* __restrict__ seas_coef, const float* __restrict__ seas_params,
    float* __restrict__ w_all, float* __restrict__ levels, int T)
{
    int lane = threadIdx.x;
    float a = 1.f / (1.f + __expf(-lvl_coef[0]));
    float g = 1.f / (1.f + __expf(-seas_coef[0]));
    float q = 1.f - a, gq = 1.f - g;

    // w_all[t] for t in [0,169): w0 pattern (w_all[168] = w0[0])
    for (int t = lane; t < T_S + 1; t += 64) w_all[t] = __expf(seas_params[t % T_S]);
    float lvl = x[0] / __expf(seas_params[0]);
    if (lane == 0) levels[0] = lvl;

    float wcur[3];
    #pragma unroll
    for (int i = 0; i < 3; ++i)
        wcur[i] = __expf(seas_params[(1 + 3 * lane + i) % T_S]);

    float q3 = q * q * q;
    float qp[6]; qp[0] = q3;
    #pragma unroll
    for (int d = 1; d < 6; ++d) qp[d] = qp[d - 1] * qp[d - 1]; // q^(3*2^d)
    float pw3l = 1.f;                                          // q^(3*lane)
    { float b = q3; int e = lane; while (e) { if (e & 1) pw3l *= b; b *= b; e >>= 1; } }

    int nch = (T - 1 + T_S - 1) / T_S;  // 596
    float xv[3], xn[3];
    #pragma unroll
    for (int i = 0; i < 3; ++i) { int t = 1 + 3 * lane + i;       xv[i] = x[min(t, T - 1)]; }
    #pragma unroll
    for (int i = 0; i < 3; ++i) { int t = 1 + T_S + 3 * lane + i; xn[i] = x[min(t, T - 1)]; }

    for (int c = 0; c < nch; ++c) {
        int t0 = 1 + T_S * c;
        int len = (T - 1) - T_S * c; if (len > T_S) len = T_S;
        // prefetch chunk c+2 (hide HBM latency behind the scan)
        float xp[3];
        #pragma unroll
        for (int i = 0; i < 3; ++i) { int t = t0 + 2 * T_S + 3 * lane + i; xp[i] = x[min(t, T - 1)]; }

        float rr[3];
        #pragma unroll
        for (int i = 0; i < 3; ++i) rr[i] = a * xv[i] * __builtin_amdgcn_rcpf(wcur[i]);
        // per-lane local affine contribution: S = q^2*r0 + q*r1 + r2
        float S = fmaf(q, fmaf(q, rr[0], rr[1]), rr[2]);
        // inclusive wave scan with constant per-lane factor q^3
        #pragma unroll
        for (int d = 0; d < 6; ++d) {
            float o = __shfl_up(S, 1u << d);
            if (lane >= (1 << d)) S = fmaf(qp[d], o, S);
        }
        float E = __shfl_up(S, 1);
        if (lane == 0) E = 0.f;
        float lv = fmaf(pw3l, lvl, E);      // level entering this lane's elements
        float lev[3];
        #pragma unroll
        for (int i = 0; i < 3; ++i) { lv = fmaf(q, lv, rr[i]); lev[i] = lv; }
        lvl = __shfl(lv, 55);               // element 167 = lane 55, i=2
        int j0 = 3 * lane;
        #pragma unroll
        for (int i = 0; i < 3; ++i) if (j0 + i < len) levels[t0 + j0 + i] = lev[i];
        #pragma unroll
        for (int i = 0; i < 3; ++i) {
            float wn = fmaf(gq, wcur[i], g * xv[i] * __builtin_amdgcn_rcpf(lev[i]));
            if (j0 + i < len) w_all[t0 + j0 + i + T_S] = wn;
            wcur[i] = wn;
        }
        #pragma unroll
        for (int i = 0; i < 3; ++i) { xv[i] = xn[i]; xn[i] = xp[i]; }
    }
}

// ---------------- elementwise: L[t]=log(x/w), loglev[t]=log(level) ----------------
__global__ __launch_bounds__(256) void post_kernel(
    const float* __restrict__ x, const float* __restrict__ w_all,
    const float* __restrict__ levels, float* __restrict__ Lf,
    float* __restrict__ loglev, int T)
{
    int t = blockIdx.x * 256 + threadIdx.x;
    if (t < T) {
        Lf[t] = __logf(x[t]) - __logf(w_all[t]);
        loglev[t] = __logf(levels[t]);
    }
}

// ---------------- level variation loss (detached scalar) ----------------
__global__ __launch_bounds__(1024) void loss_kernel(
    const float* __restrict__ loglev, const int* __restrict__ lvp,
    float* __restrict__ out_loss, int T)
{
    __shared__ float red[1024];
    float s = 0.f;
    for (int i = threadIdx.x; i < T - 2; i += 1024) {
        float d = loglev[i + 2] - 2.f * loglev[i + 1] + loglev[i];
        s = fmaf(d, d, s);
    }
    red[threadIdx.x] = s;
    __syncthreads();
    for (int w = 512; w > 0; w >>= 1) {
        if (threadIdx.x < (unsigned)w) red[threadIdx.x] += red[threadIdx.x + w];
        __syncthreads();
    }
    if (threadIdx.x == 0) out_loss[0] = red[0] * (float)lvp[0] / (float)(T - 2);
}

// ---------------- labels[n,j] = L[n+336+j] - loglev[n+336] ----------------
__global__ __launch_bounds__(256) void labels_kernel(
    const float* __restrict__ Lf, const float* __restrict__ loglev,
    float* __restrict__ lab, int N)
{
    int idx = blockIdx.x * 256 + threadIdx.x;
    if (idx < N * T_OUT) {
        int n = idx / T_OUT, j = idx - n * T_OUT;
        lab[idx] = Lf[n + T_WIN + j] - loglev[n + T_WIN];
    }
}

// ---------------- fused MLP: out = tanh(inputs@W1 + b1) @ W2 + b2 ----------------
// inputs[n,j] = L[n+j] - ll[n] folded as:  pre = (window corr of L) + b1 - ll*colsum(W1)
// Block: BM=128 rows, 256 threads = 16 row-groups (TM=8) x 16 col-groups (TN=2 / TN_out=3)
__global__ __launch_bounds__(256) void gemm_kernel(
    const float* __restrict__ Lf, const float* __restrict__ loglev,
    const float* __restrict__ W1, const float* __restrict__ b1,
    const float* __restrict__ W2, const float* __restrict__ b2,
    const float* __restrict__ cs, float* __restrict__ outp, int T, int N)
{
    __shared__ float Ls[BM + T_WIN];       // 464
    __shared__ float llv[BM];
    __shared__ float w1s[T_WIN * HC];      // 336x32
    __shared__ float w2s[HC * T_OUT];      // 32x48
    __shared__ float csb[HC], btb[HC];
    __shared__ float hs[HC][BM + 4];       // transposed hidden tile

    int tid = threadIdx.x;
    int n0 = blockIdx.x * BM;
    for (int i = tid; i < BM + T_WIN; i += 256) {
        int t = n0 + i; Ls[i] = (t < T) ? Lf[t] : 0.f;
    }
    for (int i = tid; i < BM; i += 256) {
        int t = n0 + i + T_WIN; llv[i] = (t < T) ? loglev[t] : 0.f;
    }
    int m = tid & 15, cg = tid >> 4;
    int r0 = m * 8, c0 = cg * 2, o0 = cg * 3;
    float acc2[8][3];
    #pragma unroll
    for (int i = 0; i < 8; ++i) { acc2[i][0] = 0.f; acc2[i][1] = 0.f; acc2[i][2] = 0.f; }

    for (int hc0 = 0; hc0 < T_WIN; hc0 += HC) {
        int hclen = T_WIN - hc0; if (hclen > HC) hclen = HC;
        __syncthreads();
        for (int idx = tid; idx < T_WIN * HC; idx += 256) {
            int j = idx >> 5, c = idx & 31;
            w1s[idx] = (c < hclen) ? W1[j * T_WIN + hc0 + c] : 0.f;
        }
        for (int idx = tid; idx < HC * T_OUT; idx += 256) {
            int kk = idx / T_OUT, o = idx - kk * T_OUT;
            w2s[idx] = (kk < hclen) ? W2[(hc0 + kk) * T_OUT + o] : 0.f;
        }
        if (tid < HC) {
            csb[tid] = (tid < hclen) ? cs[hc0 + tid] : 0.f;
            btb[tid] = (tid < hclen) ? b1[hc0 + tid] : 0.f;
        }
        __syncthreads();

        // --- GEMM1: pre[r0..r0+7][c0..c0+1], sliding window of Ls in registers ---
        float acc1[8][2];
        #pragma unroll
        for (int i = 0; i < 8; ++i) {
            float ll = llv[r0 + i];
            acc1[i][0] = fmaf(-ll, csb[c0],     btb[c0]);
            acc1[i][1] = fmaf(-ll, csb[c0 + 1], btb[c0 + 1]);
        }
        float wv[8];
        #pragma unroll
        for (int i = 0; i < 8; ++i) wv[i] = Ls[r0 + i];
        for (int jb = 0; jb < T_WIN; jb += 8) {
            #pragma unroll
            for (int u = 0; u < 8; ++u) {
                int j = jb + u;
                float b0v = w1s[j * HC + c0];
                float b1v = w1s[j * HC + c0 + 1];
                #pragma unroll
                for (int i = 0; i < 8; ++i) {
                    float av = wv[(u + i) & 7];
                    acc1[i][0] = fmaf(av, b0v, acc1[i][0]);
                    acc1[i][1] = fmaf(av, b1v, acc1[i][1]);
                }
                wv[u] = Ls[r0 + jb + 8 + u];   // max index 463, fits
            }
        }
        // tanh -> hs (transposed). Padded cols give pre=0 -> h=0 (and w2s=0): safe.
        #pragma unroll
        for (int i = 0; i < 8; ++i) {
            #pragma unroll
            for (int cc = 0; cc < 2; ++cc) {
                float xx = acc1[i][cc];
                float e = __expf(2.f * xx);
                float h = 1.f - 2.f * __builtin_amdgcn_rcpf(e + 1.f);
                hs[c0 + cc][r0 + i] = h;
            }
        }
        __syncthreads();
        // --- GEMM2: acc2 += h @ W2_chunk ---
        for (int kk = 0; kk < HC; ++kk) {
            float w2v[3];
            #pragma unroll
            for (int oo = 0; oo < 3; ++oo) w2v[oo] = w2s[kk * T_OUT + o0 + oo];
            const float4* hp = (const float4*)&hs[kk][r0];
            float4 h0 = hp[0], h1 = hp[1];
            float hv[8] = {h0.x, h0.y, h0.z, h0.w, h1.x, h1.y, h1.z, h1.w};
            #pragma unroll
            for (int i = 0; i < 8; ++i) {
                #pragma unroll
                for (int oo = 0; oo < 3; ++oo)
                    acc2[i][oo] = fmaf(hv[i], w2v[oo], acc2[i][oo]);
            }
        }
    }
    float bv[3] = {b2[o0], b2[o0 + 1], b2[o0 + 2]};
    #pragma unroll
    for (int i = 0; i < 8; ++i) {
        int n = n0 + r0 + i;
        if (n < N) {
            #pragma unroll
            for (int oo = 0; oo < 3; ++oo)
                outp[(size_t)n * T_OUT + o0 + oo] = acc2[i][oo] + bv[oo];
        }
    }
}

extern "C" void kernel_launch(void* const* d_in, const int* in_sizes, int n_in,
                              void* d_out, int out_size, void* d_ws, size_t ws_size,
                              hipStream_t stream) {
    const float* x    = (const float*)d_in[0];
    const float* lvlc = (const float*)d_in[1];
    const float* seac = (const float*)d_in[2];
    const float* sp   = (const float*)d_in[3];
    const float* W1   = (const float*)d_in[4];
    const float* b1   = (const float*)d_in[5];
    const float* W2   = (const float*)d_in[6];
    const float* b2   = (const float*)d_in[7];
    const int*   lvp  = (const int*)d_in[10];

    int T = in_sizes[0];
    int N = T - T_WIN - T_OUT + 1;

    float* ws     = (float*)d_ws;
    float* w_all  = ws;                      // T + 192 (scan writes up to T+167)
    float* levels = w_all + T + 192;         // T
    float* loglev = levels + T;              // T
    float* Lf     = loglev + T;              // T
    float* cs     = Lf + T;                  // 336

    float* outp  = (float*)d_out;                    // N*48
    float* lab   = outp + (size_t)N * T_OUT;         // N*48
    float* lossp = lab + (size_t)N * T_OUT;          // 1

    cs_kernel<<<(T_WIN + 63) / 64, 64, 0, stream>>>(W1, cs);
    scan_kernel<<<1, 64, 0, stream>>>(x, lvlc, seac, sp, w_all, levels, T);
    post_kernel<<<(T + 255) / 256, 256, 0, stream>>>(x, w_all, levels, Lf, loglev, T);
    loss_kernel<<<1, 1024, 0, stream>>>(loglev, lvp, lossp, T);
    labels_kernel<<<(N * T_OUT + 255) / 256, 256, 0, stream>>>(Lf, loglev, lab, N);
    gemm_kernel<<<(N + BM - 1) / BM, 256, 0, stream>>>(Lf, loglev, W1, b1, W2, b2, cs, outp, T, N);
}

// Round 5
// 640.798 us; speedup vs baseline: 1.4848x; 1.4848x over previous
//
#include <hip/hip_runtime.h>
#include <hip/hip_bf16.h>

#define T_WIN 336
#define T_OUT 48
#define T_S   168
#define BM    128

typedef __attribute__((ext_vector_type(8))) short short8;
typedef __attribute__((ext_vector_type(4))) float f32x4;

__device__ __forceinline__ short f2bf(float f) {
    union { float f; unsigned u; } v; v.f = f;
    unsigned r = v.u + 0x7FFFu + ((v.u >> 16) & 1u);
    return (short)(r >> 16);
}

// ---------------- colsum of W1 (fp32) ----------------
__global__ __launch_bounds__(64) void cs_kernel(const float* __restrict__ W1,
                                                float* __restrict__ cs) {
    int k = blockIdx.x * 64 + threadIdx.x;
    if (k < T_WIN) {
        float s = 0.f;
        for (int j = 0; j < T_WIN; ++j) s += W1[j * T_WIN + k];
        cs[k] = s;
    }
}

// ---------------- W1 transpose to bf16: W1T[c][k], rows padded to 352, cols to 384 ----------------
__global__ __launch_bounds__(256) void prep_w1t(const float* __restrict__ W1,
                                                short* __restrict__ W1T) {
    int d = blockIdx.x * 256 + threadIdx.x;        // dword index, total 384*176
    int c = d / 176, kp = d % 176, k = 2 * kp;
    unsigned short lo = 0, hi = 0;
    if (c < T_WIN) {
        if (k     < T_WIN) lo = (unsigned short)f2bf(W1[k * T_WIN + c]);
        if (k + 1 < T_WIN) hi = (unsigned short)f2bf(W1[(k + 1) * T_WIN + c]);
    }
    ((unsigned*)W1T)[d] = ((unsigned)hi << 16) | (unsigned)lo;
}

// ---------------- sequential ES scan, chunk-parallel over the S=168 lag ----------------
__global__ __launch_bounds__(64) void scan_kernel(
    const float* __restrict__ x, const float* __restrict__ lvl_coef,
    const float* __restrict__ seas_coef, const float* __restrict__ seas_params,
    float* __restrict__ w_all, float* __restrict__ levels, int T)
{
    int lane = threadIdx.x;
    float a = 1.f / (1.f + __expf(-lvl_coef[0]));
    float g = 1.f / (1.f + __expf(-seas_coef[0]));
    float q = 1.f - a, gq = 1.f - g;

    for (int t = lane; t < T_S + 1; t += 64) w_all[t] = __expf(seas_params[t % T_S]);
    float lvl = x[0] / __expf(seas_params[0]);
    if (lane == 0) levels[0] = lvl;

    float wcur[3];
    #pragma unroll
    for (int i = 0; i < 3; ++i)
        wcur[i] = __expf(seas_params[(1 + 3 * lane + i) % T_S]);

    float q3 = q * q * q;
    float qp[6]; qp[0] = q3;
    #pragma unroll
    for (int d = 1; d < 6; ++d) qp[d] = qp[d - 1] * qp[d - 1];
    float pw3l = 1.f;
    { float b = q3; int e = lane; while (e) { if (e & 1) pw3l *= b; b *= b; e >>= 1; } }

    int nch = (T - 1 + T_S - 1) / T_S;
    float xv[3], xn[3];
    #pragma unroll
    for (int i = 0; i < 3; ++i) { int t = 1 + 3 * lane + i;       xv[i] = x[min(t, T - 1)]; }
    #pragma unroll
    for (int i = 0; i < 3; ++i) { int t = 1 + T_S + 3 * lane + i; xn[i] = x[min(t, T - 1)]; }

    for (int c = 0; c < nch; ++c) {
        int t0 = 1 + T_S * c;
        int len = (T - 1) - T_S * c; if (len > T_S) len = T_S;
        float xp[3];
        #pragma unroll
        for (int i = 0; i < 3; ++i) { int t = t0 + 2 * T_S + 3 * lane + i; xp[i] = x[min(t, T - 1)]; }

        float rr[3];
        #pragma unroll
        for (int i = 0; i < 3; ++i) rr[i] = a * xv[i] * __builtin_amdgcn_rcpf(wcur[i]);
        float S = fmaf(q, fmaf(q, rr[0], rr[1]), rr[2]);
        #pragma unroll
        for (int d = 0; d < 6; ++d) {
            float o = __shfl_up(S, 1u << d);
            if (lane >= (1 << d)) S = fmaf(qp[d], o, S);
        }
        float E = __shfl_up(S, 1);
        if (lane == 0) E = 0.f;
        float lv = fmaf(pw3l, lvl, E);
        float lev[3];
        #pragma unroll
        for (int i = 0; i < 3; ++i) { lv = fmaf(q, lv, rr[i]); lev[i] = lv; }
        lvl = __shfl(lv, 55);
        int j0 = 3 * lane;
        #pragma unroll
        for (int i = 0; i < 3; ++i) if (j0 + i < len) levels[t0 + j0 + i] = lev[i];
        #pragma unroll
        for (int i = 0; i < 3; ++i) {
            float wn = fmaf(gq, wcur[i], g * xv[i] * __builtin_amdgcn_rcpf(lev[i]));
            if (j0 + i < len) w_all[t0 + j0 + i + T_S] = wn;
            wcur[i] = wn;
        }
        #pragma unroll
        for (int i = 0; i < 3; ++i) { xv[i] = xn[i]; xn[i] = xp[i]; }
    }
}

// ---------------- loglev[t] = log(level[t]) ----------------
__global__ __launch_bounds__(256) void loglev_kernel(
    const float* __restrict__ levels, float* __restrict__ loglev, int T)
{
    int t = blockIdx.x * 256 + threadIdx.x;
    if (t < T) loglev[t] = __logf(levels[t]);
}

// ---------------- level variation loss, two-stage ----------------
__global__ __launch_bounds__(256) void loss1_kernel(
    const float* __restrict__ loglev, float* __restrict__ part, int T)
{
    __shared__ float red[256];
    float s = 0.f;
    for (int i = blockIdx.x * 256 + threadIdx.x; i < T - 2; i += 256 * 128) {
        float d = loglev[i + 2] - 2.f * loglev[i + 1] + loglev[i];
        s = fmaf(d, d, s);
    }
    red[threadIdx.x] = s;
    __syncthreads();
    for (int w = 128; w > 0; w >>= 1) {
        if (threadIdx.x < (unsigned)w) red[threadIdx.x] += red[threadIdx.x + w];
        __syncthreads();
    }
    if (threadIdx.x == 0) part[blockIdx.x] = red[0];
}

__global__ __launch_bounds__(128) void loss2_kernel(
    const float* __restrict__ part, const int* __restrict__ lvp,
    float* __restrict__ out_loss, int T)
{
    __shared__ float red[128];
    red[threadIdx.x] = part[threadIdx.x];
    __syncthreads();
    for (int w = 64; w > 0; w >>= 1) {
        if (threadIdx.x < (unsigned)w) red[threadIdx.x] += red[threadIdx.x + w];
        __syncthreads();
    }
    if (threadIdx.x == 0) out_loss[0] = red[0] * (float)lvp[0] / (float)(T - 2);
}

// ---------------- labels[n,j] = log(x[t]) - log(w[t]) - loglev[n+336], t=n+336+j ----------------
__global__ __launch_bounds__(256) void labels_kernel(
    const float* __restrict__ x, const float* __restrict__ w_all,
    const float* __restrict__ loglev, float* __restrict__ lab, int N)
{
    int idx = blockIdx.x * 256 + threadIdx.x;
    if (idx < N * T_OUT) {
        int n = idx / T_OUT, j = idx - n * T_OUT;
        int t = n + T_WIN + j;
        lab[idx] = __logf(x[t]) - __logf(w_all[t]) - loglev[n + T_WIN];
    }
}

// ---------------- fused MLP: MFMA GEMM1 + fp32 VALU GEMM2, BLOCK-CENTERED bf16 ----------------
// L and ll random-walk to O(10) magnitude (ES neutral-mode drift); quantizing raw L to
// bf16 cost ~0.15 absmax (rounds 2-4). Fix: fold per-block constant C = loglev[n0+336]:
//   pre = sum_j bf16(L[n+j]-C)*bf16(W1[j,c]) + b1[c] - (ll[n]-C)*cs[c]   (exact identity)
__global__ __launch_bounds__(256) void gemm_kernel(
    const float* __restrict__ x, const float* __restrict__ w_all,
    const float* __restrict__ loglev,
    const short* __restrict__ W1T,
    const float* __restrict__ b1, const float* __restrict__ cs,
    const float* __restrict__ W2, const float* __restrict__ b2,
    float* __restrict__ outp, int T, int N)
{
    __shared__ float Lsf[480];
    __shared__ float llv[BM];
    __shared__ float hT[64 * 132];     // h transposed: [c_local][row], 33792 B
    __shared__ float w2s[64 * T_OUT];  // 12288 B

    int tid = threadIdx.x;
    int lane = tid & 63, wv = tid >> 6;
    int lr = lane & 15, lq = lane >> 4;
    int n0 = blockIdx.x * BM;
    int rw = wv * 32;

    float C = loglev[n0 + T_WIN];      // block centering constant (always in-range)

    for (int i = tid; i < 480; i += 256) {
        int t = n0 + i;
        Lsf[i] = (i < 464 && t < T) ? (__logf(x[t]) - __logf(w_all[t]) - C) : 0.f;
    }
    for (int i = tid; i < BM; i += 256) {
        int t = n0 + i + T_WIN;
        llv[i] = (t < T) ? (loglev[t] - C) : 0.f;
    }
    __syncthreads();

    // pack the 22 A-fragments (rows rw..rw+31, K=0..351) into registers
    short8 af[11][2];
    #pragma unroll
    for (int kt = 0; kt < 11; ++kt) {
        #pragma unroll
        for (int mt = 0; mt < 2; ++mt) {
            int E = rw + mt * 16 + lr + kt * 32 + lq * 8;
            union { short8 s; short e[8]; } u;
            #pragma unroll
            for (int j = 0; j < 8; ++j) u.e[j] = f2bf(Lsf[E + j]);
            af[kt][mt] = u.s;
        }
    }

    // fp32 GEMM2 thread mapping
    int m2 = tid & 15, cg2 = tid >> 4;
    int r0 = m2 * 8, o0 = cg2 * 3;
    float acc2[8][3];
    #pragma unroll
    for (int i = 0; i < 8; ++i) { acc2[i][0] = 0.f; acc2[i][1] = 0.f; acc2[i][2] = 0.f; }

    f32x4 zero4 = {0.f, 0.f, 0.f, 0.f};

    for (int c = 0; c < 6; ++c) {
        __syncthreads();   // previous chunk's GEMM2 reads of hT/w2s complete
        // stage this chunk's W2 rows (fp32)
        for (int idx = tid; idx < 64 * T_OUT; idx += 256) {
            int kk = idx / T_OUT, o = idx - kk * T_OUT;
            int krow = c * 64 + kk;
            w2s[idx] = (krow < T_WIN) ? W2[krow * T_OUT + o] : 0.f;
        }
        // per-col fold constants
        float b1v[4], csv[4];
        #pragma unroll
        for (int ct = 0; ct < 4; ++ct) {
            int col = c * 64 + ct * 16 + lr;
            b1v[ct] = (col < T_WIN) ? b1[col] : 0.f;
            csv[ct] = (col < T_WIN) ? cs[col] : 0.f;
        }

        // --- GEMM1: 128x64 tile, K=352 (zero-padded), B-frags straight from W1T ---
        f32x4 acc1[2][4];
        #pragma unroll
        for (int mt = 0; mt < 2; ++mt)
            #pragma unroll
            for (int ct = 0; ct < 4; ++ct) acc1[mt][ct] = zero4;

        #pragma unroll
        for (int kt = 0; kt < 11; ++kt) {
            #pragma unroll
            for (int ct = 0; ct < 4; ++ct) {
                int colg = c * 64 + ct * 16 + lr;          // < 384
                short8 bf = *(const short8*)&W1T[colg * 352 + kt * 32 + lq * 8];
                acc1[0][ct] = __builtin_amdgcn_mfma_f32_16x16x32_bf16(af[kt][0], bf, acc1[0][ct], 0, 0, 0);
                acc1[1][ct] = __builtin_amdgcn_mfma_f32_16x16x32_bf16(af[kt][1], bf, acc1[1][ct], 0, 0, 0);
            }
        }
        // epilogue: fold + tanh -> hT fp32 [c_local][row]
        #pragma unroll
        for (int mt = 0; mt < 2; ++mt)
            #pragma unroll
            for (int ct = 0; ct < 4; ++ct)
                #pragma unroll
                for (int r = 0; r < 4; ++r) {
                    int row = rw + mt * 16 + lq * 4 + r;
                    float pre = acc1[mt][ct][r] + b1v[ct] - llv[row] * csv[ct];
                    float e = __expf(2.f * pre);
                    float h = 1.f - 2.f * __builtin_amdgcn_rcpf(e + 1.f);
                    hT[(ct * 16 + lr) * 132 + row] = h;
                }
        __syncthreads();   // hT + w2s visible

        // --- GEMM2 (fp32 VALU): acc2 += h @ W2chunk ---
        for (int kk = 0; kk < 64; ++kk) {
            float w2v[3];
            #pragma unroll
            for (int oo = 0; oo < 3; ++oo) w2v[oo] = w2s[kk * T_OUT + o0 + oo];
            const float4* hp = (const float4*)&hT[kk * 132 + r0];
            float4 h0 = hp[0], h1 = hp[1];
            float hv[8] = {h0.x, h0.y, h0.z, h0.w, h1.x, h1.y, h1.z, h1.w};
            #pragma unroll
            for (int i = 0; i < 8; ++i)
                #pragma unroll
                for (int oo = 0; oo < 3; ++oo)
                    acc2[i][oo] = fmaf(hv[i], w2v[oo], acc2[i][oo]);
        }
    }

    float bv[3] = {b2[o0], b2[o0 + 1], b2[o0 + 2]};
    #pragma unroll
    for (int i = 0; i < 8; ++i) {
        int n = n0 + r0 + i;
        if (n < N) {
            #pragma unroll
            for (int oo = 0; oo < 3; ++oo)
                outp[(size_t)n * T_OUT + o0 + oo] = acc2[i][oo] + bv[oo];
        }
    }
}

extern "C" void kernel_launch(void* const* d_in, const int* in_sizes, int n_in,
                              void* d_out, int out_size, void* d_ws, size_t ws_size,
                              hipStream_t stream) {
    const float* x    = (const float*)d_in[0];
    const float* lvlc = (const float*)d_in[1];
    const float* seac = (const float*)d_in[2];
    const float* sp   = (const float*)d_in[3];
    const float* W1   = (const float*)d_in[4];
    const float* b1   = (const float*)d_in[5];
    const float* W2   = (const float*)d_in[6];
    const float* b2   = (const float*)d_in[7];
    const int*   lvp  = (const int*)d_in[10];

    int T = in_sizes[0];
    int N = T - T_WIN - T_OUT + 1;

    // ws footprint: 270336 B (W1T) + (3T + 672 + 192) floats ~= 1.47 MB
    short* W1T    = (short*)d_ws;                  // 384*352 shorts, 16B-aligned
    float* w_all  = (float*)(W1T + 384 * 352);     // T + 192
    float* levels = w_all + T + 192;               // T
    float* loglev = levels + T;                    // T
    float* cs     = loglev + T;                    // 352
    float* lpart  = cs + 352;                      // 128

    float* outp  = (float*)d_out;
    float* lab   = outp + (size_t)N * T_OUT;
    float* lossp = lab + (size_t)N * T_OUT;

    prep_w1t<<<264, 256, 0, stream>>>(W1, W1T);
    cs_kernel<<<(T_WIN + 63) / 64, 64, 0, stream>>>(W1, cs);
    scan_kernel<<<1, 64, 0, stream>>>(x, lvlc, seac, sp, w_all, levels, T);
    loglev_kernel<<<(T + 255) / 256, 256, 0, stream>>>(levels, loglev, T);
    loss1_kernel<<<128, 256, 0, stream>>>(loglev, lpart, T);
    loss2_kernel<<<1, 128, 0, stream>>>(lpart, lvp, lossp, T);
    labels_kernel<<<(N * T_OUT + 255) / 256, 256, 0, stream>>>(x, w_all, loglev, lab, N);
    gemm_kernel<<<(N + BM - 1) / BM, 256, 0, stream>>>(x, w_all, loglev, W1T, b1, cs, W2, b2, outp, T, N);
}

// Round 7
// 512.897 us; speedup vs baseline: 1.8550x; 1.2494x over previous
//
#include <hip/hip_runtime.h>
#include <hip/hip_bf16.h>

#define T_WIN 336
#define T_OUT 48
#define T_S   168
#define BM    128

typedef __attribute__((ext_vector_type(8))) short short8;
typedef __attribute__((ext_vector_type(4))) float f32x4;

__device__ __forceinline__ short f2bf(float f) {
    union { float f; unsigned u; } v; v.f = f;
    unsigned r = v.u + 0x7FFFu + ((v.u >> 16) & 1u);
    return (short)(r >> 16);
}

template <int CTRL, int RMASK>
__device__ __forceinline__ float dppf(float v) {
    union { float f; int i; } in, out;
    in.f = v;
    out.i = __builtin_amdgcn_update_dpp(0, in.i, CTRL, RMASK, 0xf, true);
    return out.f;
}

// ---------------- colsum of W1 (fp32) ----------------
__global__ __launch_bounds__(64) void cs_kernel(const float* __restrict__ W1,
                                                float* __restrict__ cs) {
    int k = blockIdx.x * 64 + threadIdx.x;
    if (k < T_WIN) {
        float s = 0.f;
        for (int j = 0; j < T_WIN; ++j) s += W1[j * T_WIN + k];
        cs[k] = s;
    }
}

// ---------------- W1 transpose to bf16: W1T[c][k], rows padded to 352, cols to 384 ----------------
__global__ __launch_bounds__(256) void prep_w1t(const float* __restrict__ W1,
                                                short* __restrict__ W1T) {
    int d = blockIdx.x * 256 + threadIdx.x;        // dword index, total 384*176
    int c = d / 176, kp = d % 176, k = 2 * kp;
    unsigned short lo = 0, hi = 0;
    if (c < T_WIN) {
        if (k     < T_WIN) lo = (unsigned short)f2bf(W1[k * T_WIN + c]);
        if (k + 1 < T_WIN) hi = (unsigned short)f2bf(W1[(k + 1) * T_WIN + c]);
    }
    ((unsigned*)W1T)[d] = ((unsigned)hi << 16) | (unsigned)lo;
}

// ---------------- sequential ES scan, chunk-parallel over the S=168 lag ----------------
// Serial across 596 chunks (seasonal state has long memory; chunk-parallel warm-up fails
// on smooth-phase modes with |lambda|~0.996/chunk). Critical path minimized with DPP:
// row_shr scans (bound_ctrl zero-fill, branchless), row_bcast cross-row, wave_shr exclusive.
__global__ __launch_bounds__(64) void scan_kernel(
    const float* __restrict__ x, const float* __restrict__ lvl_coef,
    const float* __restrict__ seas_coef, const float* __restrict__ seas_params,
    float* __restrict__ w_all, float* __restrict__ levels, int T)
{
    int lane = threadIdx.x;
    float a = 1.f / (1.f + __expf(-lvl_coef[0]));
    float g = 1.f / (1.f + __expf(-seas_coef[0]));
    float q = 1.f - a, gq = 1.f - g;

    for (int t = lane; t < T_S + 1; t += 64) w_all[t] = __expf(seas_params[t % T_S]);
    float lvl = x[0] / __expf(seas_params[0]);
    if (lane == 0) levels[0] = lvl;

    float wcur[3];
    #pragma unroll
    for (int i = 0; i < 3; ++i)
        wcur[i] = __expf(seas_params[(1 + 3 * lane + i) % T_S]);

    // scan factors: distance-d contribution carries q^(3d)
    float f1 = q * q * q;
    float f2 = f1 * f1, f4 = f2 * f2, f8 = f4 * f4;
    float lnq = __logf(q);                                       // q in (0,1): safe
    float P15 = __expf(3.f * (float)((lane & 15) + 1) * lnq);    // row_bcast:15 factor
    float P31 = __expf(3.f * (float)((lane & 31) + 1) * lnq);    // row_bcast:31 factor
    float pw3l = __expf(3.f * (float)lane * lnq);                // q^(3*lane)

    int nch = (T - 1 + T_S - 1) / T_S;  // 596; chunks 0..594 full, 595 partial
    float xv[3], xn[3];
    #pragma unroll
    for (int i = 0; i < 3; ++i) { int t = 1 + 3 * lane + i;       xv[i] = x[min(t, T - 1)]; }
    #pragma unroll
    for (int i = 0; i < 3; ++i) { int t = 1 + T_S + 3 * lane + i; xn[i] = x[min(t, T - 1)]; }

    int j0 = 3 * lane;
    bool wr = (lane < 56);   // lanes 56..63 are scan-padding only

    for (int c = 0; c < nch; ++c) {
        int t0 = 1 + T_S * c;
        int len = (T - 1) - T_S * c; if (len > T_S) len = T_S;
        bool full = (len == T_S);
        // prefetch chunk c+2
        float xp[3];
        #pragma unroll
        for (int i = 0; i < 3; ++i) { int t = t0 + 2 * T_S + 3 * lane + i; xp[i] = x[min(t, T - 1)]; }

        float rr[3];
        #pragma unroll
        for (int i = 0; i < 3; ++i) rr[i] = a * xv[i] * __builtin_amdgcn_rcpf(wcur[i]);
        // lane-local affine contribution, then branchless DPP affine scan (factor q^3/lane)
        float S = fmaf(q, fmaf(q, rr[0], rr[1]), rr[2]);
        S = fmaf(f1, dppf<0x111, 0xf>(S), S);   // row_shr:1
        S = fmaf(f2, dppf<0x112, 0xf>(S), S);   // row_shr:2
        S = fmaf(f4, dppf<0x114, 0xf>(S), S);   // row_shr:4
        S = fmaf(f8, dppf<0x118, 0xf>(S), S);   // row_shr:8
        S = fmaf(P15, dppf<0x142, 0xa>(S), S);  // row_bcast:15 -> rows 1,3
        S = fmaf(P31, dppf<0x143, 0xc>(S), S);  // row_bcast:31 -> rows 2,3
        float E = dppf<0x138, 0xf>(S);          // wave_shr:1 (exclusive; lane0 -> 0)

        float lv = fmaf(pw3l, lvl, E);
        float lev[3];
        #pragma unroll
        for (int i = 0; i < 3; ++i) { lv = fmaf(q, lv, rr[i]); lev[i] = lv; }
        { union { float f; int i; } u; u.i = __builtin_amdgcn_readlane(__builtin_bit_cast(int, lev[2]), 55); lvl = u.f; }

        float wn[3];
        #pragma unroll
        for (int i = 0; i < 3; ++i)
            wn[i] = fmaf(gq, wcur[i], g * xv[i] * __builtin_amdgcn_rcpf(lev[i]));

        if (full) {
            if (wr) {
                #pragma unroll
                for (int i = 0; i < 3; ++i) {
                    levels[t0 + j0 + i] = lev[i];
                    w_all[t0 + j0 + i + T_S] = wn[i];
                }
            }
        } else {
            #pragma unroll
            for (int i = 0; i < 3; ++i) {
                if (j0 + i < len) {
                    levels[t0 + j0 + i] = lev[i];
                    w_all[t0 + j0 + i + T_S] = wn[i];
                }
            }
        }
        #pragma unroll
        for (int i = 0; i < 3; ++i) { wcur[i] = wn[i]; xv[i] = xn[i]; xn[i] = xp[i]; }
    }
}

// ---------------- loglev[t] = log(level[t]) ----------------
__global__ __launch_bounds__(256) void loglev_kernel(
    const float* __restrict__ levels, float* __restrict__ loglev, int T)
{
    int t = blockIdx.x * 256 + threadIdx.x;
    if (t < T) loglev[t] = __logf(levels[t]);
}

// ---------------- level variation loss, two-stage ----------------
__global__ __launch_bounds__(256) void loss1_kernel(
    const float* __restrict__ loglev, float* __restrict__ part, int T)
{
    __shared__ float red[256];
    float s = 0.f;
    for (int i = blockIdx.x * 256 + threadIdx.x; i < T - 2; i += 256 * 128) {
        float d = loglev[i + 2] - 2.f * loglev[i + 1] + loglev[i];
        s = fmaf(d, d, s);
    }
    red[threadIdx.x] = s;
    __syncthreads();
    for (int w = 128; w > 0; w >>= 1) {
        if (threadIdx.x < (unsigned)w) red[threadIdx.x] += red[threadIdx.x + w];
        __syncthreads();
    }
    if (threadIdx.x == 0) part[blockIdx.x] = red[0];
}

__global__ __launch_bounds__(128) void loss2_kernel(
    const float* __restrict__ part, const int* __restrict__ lvp,
    float* __restrict__ out_loss, int T)
{
    __shared__ float red[128];
    red[threadIdx.x] = part[threadIdx.x];
    __syncthreads();
    for (int w = 64; w > 0; w >>= 1) {
        if (threadIdx.x < (unsigned)w) red[threadIdx.x] += red[threadIdx.x + w];
        __syncthreads();
    }
    if (threadIdx.x == 0) out_loss[0] = red[0] * (float)lvp[0] / (float)(T - 2);
}

// ---------------- labels[n,j] = log(x[t]) - log(w[t]) - loglev[n+336], t=n+336+j ----------------
__global__ __launch_bounds__(256) void labels_kernel(
    const float* __restrict__ x, const float* __restrict__ w_all,
    const float* __restrict__ loglev, float* __restrict__ lab, int N)
{
    int idx = blockIdx.x * 256 + threadIdx.x;
    if (idx < N * T_OUT) {
        int n = idx / T_OUT, j = idx - n * T_OUT;
        int t = n + T_WIN + j;
        lab[idx] = __logf(x[t]) - __logf(w_all[t]) - loglev[n + T_WIN];
    }
}

// ---------------- fused MLP: MFMA GEMM1 + fp32 VALU GEMM2, BLOCK-CENTERED bf16 ----------------
// L and ll random-walk to O(10) magnitude (ES neutral-mode drift); quantizing raw L to
// bf16 cost ~0.15 absmax (rounds 2-4). Fix: fold per-block constant C = loglev[n0+336]:
//   pre = sum_j bf16(L[n+j]-C)*bf16(W1[j,c]) + b1[c] - (ll[n]-C)*cs[c]   (exact identity)
__global__ __launch_bounds__(256) void gemm_kernel(
    const float* __restrict__ x, const float* __restrict__ w_all,
    const float* __restrict__ loglev,
    const short* __restrict__ W1T,
    const float* __restrict__ b1, const float* __restrict__ cs,
    const float* __restrict__ W2, const float* __restrict__ b2,
    float* __restrict__ outp, int T, int N)
{
    __shared__ float Lsf[480];
    __shared__ float llv[BM];
    __shared__ float hT[64 * 132];     // h transposed: [c_local][row], 33792 B
    __shared__ float w2s[64 * T_OUT];  // 12288 B

    int tid = threadIdx.x;
    int lane = tid & 63, wv = tid >> 6;
    int lr = lane & 15, lq = lane >> 4;
    int n0 = blockIdx.x * BM;
    int rw = wv * 32;

    float C = loglev[n0 + T_WIN];      // block centering constant (always in-range)

    for (int i = tid; i < 480; i += 256) {
        int t = n0 + i;
        Lsf[i] = (i < 464 && t < T) ? (__logf(x[t]) - __logf(w_all[t]) - C) : 0.f;
    }
    for (int i = tid; i < BM; i += 256) {
        int t = n0 + i + T_WIN;
        llv[i] = (t < T) ? (loglev[t] - C) : 0.f;
    }
    __syncthreads();

    // pack the 22 A-fragments (rows rw..rw+31, K=0..351) into registers
    short8 af[11][2];
    #pragma unroll
    for (int kt = 0; kt < 11; ++kt) {
        #pragma unroll
        for (int mt = 0; mt < 2; ++mt) {
            int E = rw + mt * 16 + lr + kt * 32 + lq * 8;
            union { short8 s; short e[8]; } u;
            #pragma unroll
            for (int j = 0; j < 8; ++j) u.e[j] = f2bf(Lsf[E + j]);
            af[kt][mt] = u.s;
        }
    }

    // fp32 GEMM2 thread mapping
    int m2 = tid & 15, cg2 = tid >> 4;
    int r0 = m2 * 8, o0 = cg2 * 3;
    float acc2[8][3];
    #pragma unroll
    for (int i = 0; i < 8; ++i) { acc2[i][0] = 0.f; acc2[i][1] = 0.f; acc2[i][2] = 0.f; }

    f32x4 zero4 = {0.f, 0.f, 0.f, 0.f};

    for (int c = 0; c < 6; ++c) {
        __syncthreads();   // previous chunk's GEMM2 reads of hT/w2s complete
        // stage this chunk's W2 rows (fp32)
        for (int idx = tid; idx < 64 * T_OUT; idx += 256) {
            int kk = idx / T_OUT, o = idx - kk * T_OUT;
            int krow = c * 64 + kk;
            w2s[idx] = (krow < T_WIN) ? W2[krow * T_OUT + o] : 0.f;
        }
        // per-col fold constants
        float b1v[4], csv[4];
        #pragma unroll
        for (int ct = 0; ct < 4; ++ct) {
            int col = c * 64 + ct * 16 + lr;
            b1v[ct] = (col < T_WIN) ? b1[col] : 0.f;
            csv[ct] = (col < T_WIN) ? cs[col] : 0.f;
        }

        // --- GEMM1: 128x64 tile, K=352 (zero-padded), B-frags straight from W1T ---
        f32x4 acc1[2][4];
        #pragma unroll
        for (int mt = 0; mt < 2; ++mt)
            #pragma unroll
            for (int ct = 0; ct < 4; ++ct) acc1[mt][ct] = zero4;

        #pragma unroll
        for (int kt = 0; kt < 11; ++kt) {
            #pragma unroll
            for (int ct = 0; ct < 4; ++ct) {
                int colg = c * 64 + ct * 16 + lr;          // < 384
                short8 bf = *(const short8*)&W1T[colg * 352 + kt * 32 + lq * 8];
                acc1[0][ct] = __builtin_amdgcn_mfma_f32_16x16x32_bf16(af[kt][0], bf, acc1[0][ct], 0, 0, 0);
                acc1[1][ct] = __builtin_amdgcn_mfma_f32_16x16x32_bf16(af[kt][1], bf, acc1[1][ct], 0, 0, 0);
            }
        }
        // epilogue: fold + tanh -> hT fp32 [c_local][row]
        #pragma unroll
        for (int mt = 0; mt < 2; ++mt)
            #pragma unroll
            for (int ct = 0; ct < 4; ++ct)
                #pragma unroll
                for (int r = 0; r < 4; ++r) {
                    int row = rw + mt * 16 + lq * 4 + r;
                    float pre = acc1[mt][ct][r] + b1v[ct] - llv[row] * csv[ct];
                    float e = __expf(2.f * pre);
                    float h = 1.f - 2.f * __builtin_amdgcn_rcpf(e + 1.f);
                    hT[(ct * 16 + lr) * 132 + row] = h;
                }
        __syncthreads();   // hT + w2s visible

        // --- GEMM2 (fp32 VALU): acc2 += h @ W2chunk ---
        for (int kk = 0; kk < 64; ++kk) {
            float w2v[3];
            #pragma unroll
            for (int oo = 0; oo < 3; ++oo) w2v[oo] = w2s[kk * T_OUT + o0 + oo];
            const float4* hp = (const float4*)&hT[kk * 132 + r0];
            float4 h0 = hp[0], h1 = hp[1];
            float hv[8] = {h0.x, h0.y, h0.z, h0.w, h1.x, h1.y, h1.z, h1.w};
            #pragma unroll
            for (int i = 0; i < 8; ++i)
                #pragma unroll
                for (int oo = 0; oo < 3; ++oo)
                    acc2[i][oo] = fmaf(hv[i], w2v[oo], acc2[i][oo]);
        }
    }

    float bv[3] = {b2[o0], b2[o0 + 1], b2[o0 + 2]};
    #pragma unroll
    for (int i = 0; i < 8; ++i) {
        int n = n0 + r0 + i;
        if (n < N) {
            #pragma unroll
            for (int oo = 0; oo < 3; ++oo)
                outp[(size_t)n * T_OUT + o0 + oo] = acc2[i][oo] + bv[oo];
        }
    }
}

extern "C" void kernel_launch(void* const* d_in, const int* in_sizes, int n_in,
                              void* d_out, int out_size, void* d_ws, size_t ws_size,
                              hipStream_t stream) {
    const float* x    = (const float*)d_in[0];
    const float* lvlc = (const float*)d_in[1];
    const float* seac = (const float*)d_in[2];
    const float* sp   = (const float*)d_in[3];
    const float* W1   = (const float*)d_in[4];
    const float* b1   = (const float*)d_in[5];
    const float* W2   = (const float*)d_in[6];
    const float* b2   = (const float*)d_in[7];
    const int*   lvp  = (const int*)d_in[10];

    int T = in_sizes[0];
    int N = T - T_WIN - T_OUT + 1;

    // ws footprint: 270336 B (W1T) + (3T + 672 + 192) floats ~= 1.47 MB
    short* W1T    = (short*)d_ws;                  // 384*352 shorts, 16B-aligned
    float* w_all  = (float*)(W1T + 384 * 352);     // T + 192
    float* levels = w_all + T + 192;               // T
    float* loglev = levels + T;                    // T
    float* cs     = loglev + T;                    // 352
    float* lpart  = cs + 352;                      // 128

    float* outp  = (float*)d_out;
    float* lab   = outp + (size_t)N * T_OUT;
    float* lossp = lab + (size_t)N * T_OUT;

    prep_w1t<<<264, 256, 0, stream>>>(W1, W1T);
    cs_kernel<<<(T_WIN + 63) / 64, 64, 0, stream>>>(W1, cs);
    scan_kernel<<<1, 64, 0, stream>>>(x, lvlc, seac, sp, w_all, levels, T);
    loglev_kernel<<<(T + 255) / 256, 256, 0, stream>>>(levels, loglev, T);
    loss1_kernel<<<128, 256, 0, stream>>>(loglev, lpart, T);
    loss2_kernel<<<1, 128, 0, stream>>>(lpart, lvp, lossp, T);
    labels_kernel<<<(N * T_OUT + 255) / 256, 256, 0, stream>>>(x, w_all, loglev, lab, N);
    gemm_kernel<<<(N + BM - 1) / BM, 256, 0, stream>>>(x, w_all, loglev, W1T, b1, cs, W2, b2, outp, T, N);
}

// Round 8
// 455.476 us; speedup vs baseline: 2.0889x; 1.1261x over previous
//
#include <hip/hip_runtime.h>
#include <hip/hip_bf16.h>

#define T_WIN 336
#define T_OUT 48
#define T_S   168
#define BM    128

typedef __attribute__((ext_vector_type(8))) short short8;
typedef __attribute__((ext_vector_type(4))) float f32x4;

__device__ __forceinline__ short f2bf(float f) {
    union { float f; unsigned u; } v; v.f = f;
    unsigned r = v.u + 0x7FFFu + ((v.u >> 16) & 1u);
    return (short)(r >> 16);
}

template <int CTRL, int RMASK>
__device__ __forceinline__ float dppf(float v) {
    union { float f; int i; } in, out;
    in.f = v;
    out.i = __builtin_amdgcn_update_dpp(0, in.i, CTRL, RMASK, 0xf, true);
    return out.f;
}

// ---------------- colsum of W1 (fp32) ----------------
__global__ __launch_bounds__(64) void cs_kernel(const float* __restrict__ W1,
                                                float* __restrict__ cs) {
    int k = blockIdx.x * 64 + threadIdx.x;
    if (k < T_WIN) {
        float s = 0.f;
        for (int j = 0; j < T_WIN; ++j) s += W1[j * T_WIN + k];
        cs[k] = s;
    }
}

// ---------------- W1 transpose to bf16: W1T[c][k], rows padded to 352, cols to 384 ----------------
__global__ __launch_bounds__(256) void prep_w1t(const float* __restrict__ W1,
                                                short* __restrict__ W1T) {
    int d = blockIdx.x * 256 + threadIdx.x;        // dword index, total 384*176
    int c = d / 176, kp = d % 176, k = 2 * kp;
    unsigned short lo = 0, hi = 0;
    if (c < T_WIN) {
        if (k     < T_WIN) lo = (unsigned short)f2bf(W1[k * T_WIN + c]);
        if (k + 1 < T_WIN) hi = (unsigned short)f2bf(W1[(k + 1) * T_WIN + c]);
    }
    ((unsigned*)W1T)[d] = ((unsigned)hi << 16) | (unsigned)lo;
}

// ---------------- sequential ES scan, chunk-parallel over the S=168 lag ----------------
// Serial across 596 chunks. Round-7 lesson (VGPR_Count=20): default occupancy-driven
// regalloc sank the x prefetch loads to use sites -> one cold ~900cy HBM miss per chunk
// (~224us, matched measurement). Fix: __launch_bounds__(64,1) frees the VGPR budget +
// group-of-4 unrolled x pipeline (xh prefetched a full group ahead, 12 pipelined loads).
__global__ __launch_bounds__(64, 1) void scan_kernel(
    const float* __restrict__ x, const float* __restrict__ lvl_coef,
    const float* __restrict__ seas_coef, const float* __restrict__ seas_params,
    float* __restrict__ w_all, float* __restrict__ levels, int T)
{
    int lane = threadIdx.x;
    float a = 1.f / (1.f + __expf(-lvl_coef[0]));
    float g = 1.f / (1.f + __expf(-seas_coef[0]));
    float q = 1.f - a, gq = 1.f - g;

    for (int t = lane; t < T_S + 1; t += 64) w_all[t] = __expf(seas_params[t % T_S]);
    float lvl = x[0] / __expf(seas_params[0]);
    if (lane == 0) levels[0] = lvl;

    float wcur[3];
    #pragma unroll
    for (int i = 0; i < 3; ++i)
        wcur[i] = __expf(seas_params[(1 + 3 * lane + i) % T_S]);

    // scan factors: distance-d contribution carries q^(3d)
    float f1 = q * q * q;
    float f2 = f1 * f1, f4 = f2 * f2, f8 = f4 * f4;
    float lnq = __logf(q);                                       // q in (0,1): safe
    float P15 = __expf(3.f * (float)((lane & 15) + 1) * lnq);    // row_bcast:15 factor
    float P31 = __expf(3.f * (float)((lane & 31) + 1) * lnq);    // row_bcast:31 factor
    float pw3l = __expf(3.f * (float)lane * lnq);                // q^(3*lane)

    int nch = (T - 1 + T_S - 1) / T_S;  // 596 = 4*149; chunks 0..594 full, 595 partial
    int ngrp = (nch + 3) / 4;
    int j0 = 3 * lane;
    bool wr = (lane < 56);   // lanes 56..63 are scan-padding only

    float xg[4][3], xh[4][3];
    #pragma unroll
    for (int u = 0; u < 4; ++u)
        #pragma unroll
        for (int i = 0; i < 3; ++i)
            xg[u][i] = x[min(1 + T_S * u + j0 + i, T - 1)];

    for (int grp = 0; grp < ngrp; ++grp) {
        // prefetch next group's 12 x values (pipelined; used ~2500cy later)
        #pragma unroll
        for (int u = 0; u < 4; ++u)
            #pragma unroll
            for (int i = 0; i < 3; ++i) {
                int t = 1 + T_S * (4 * (grp + 1) + u) + j0 + i;
                xh[u][i] = x[min(t, T - 1)];
            }

        #pragma unroll
        for (int u = 0; u < 4; ++u) {
            int c = 4 * grp + u;
            int t0 = 1 + T_S * c;
            int len = (T - 1) - T_S * c; if (len > T_S) len = T_S;
            bool full = (len == T_S);

            float rr[3];
            #pragma unroll
            for (int i = 0; i < 3; ++i) rr[i] = a * xg[u][i] * __builtin_amdgcn_rcpf(wcur[i]);
            // lane-local affine contribution, then branchless DPP affine scan (factor q^3/lane)
            float S = fmaf(q, fmaf(q, rr[0], rr[1]), rr[2]);
            S = fmaf(f1, dppf<0x111, 0xf>(S), S);   // row_shr:1
            S = fmaf(f2, dppf<0x112, 0xf>(S), S);   // row_shr:2
            S = fmaf(f4, dppf<0x114, 0xf>(S), S);   // row_shr:4
            S = fmaf(f8, dppf<0x118, 0xf>(S), S);   // row_shr:8
            S = fmaf(P15, dppf<0x142, 0xa>(S), S);  // row_bcast:15 -> rows 1,3
            S = fmaf(P31, dppf<0x143, 0xc>(S), S);  // row_bcast:31 -> rows 2,3
            float E = dppf<0x138, 0xf>(S);          // wave_shr:1 (exclusive; lane0 -> 0)

            float lv = fmaf(pw3l, lvl, E);
            float lev[3];
            #pragma unroll
            for (int i = 0; i < 3; ++i) { lv = fmaf(q, lv, rr[i]); lev[i] = lv; }
            { union { float f; int i; } uu; uu.i = __builtin_amdgcn_readlane(__builtin_bit_cast(int, lev[2]), 55); lvl = uu.f; }

            float wn[3];
            #pragma unroll
            for (int i = 0; i < 3; ++i)
                wn[i] = fmaf(gq, wcur[i], g * xg[u][i] * __builtin_amdgcn_rcpf(lev[i]));

            if (full) {
                if (wr) {
                    #pragma unroll
                    for (int i = 0; i < 3; ++i) {
                        levels[t0 + j0 + i] = lev[i];
                        w_all[t0 + j0 + i + T_S] = wn[i];
                    }
                }
            } else {
                #pragma unroll
                for (int i = 0; i < 3; ++i) {
                    if (j0 + i < len) {
                        levels[t0 + j0 + i] = lev[i];
                        w_all[t0 + j0 + i + T_S] = wn[i];
                    }
                }
            }
            #pragma unroll
            for (int i = 0; i < 3; ++i) wcur[i] = wn[i];
        }
        #pragma unroll
        for (int u = 0; u < 4; ++u)
            #pragma unroll
            for (int i = 0; i < 3; ++i) xg[u][i] = xh[u][i];
    }
}

// ---------------- loglev[t] = log(level[t]) ----------------
__global__ __launch_bounds__(256) void loglev_kernel(
    const float* __restrict__ levels, float* __restrict__ loglev, int T)
{
    int t = blockIdx.x * 256 + threadIdx.x;
    if (t < T) loglev[t] = __logf(levels[t]);
}

// ---------------- level variation loss, two-stage ----------------
__global__ __launch_bounds__(256) void loss1_kernel(
    const float* __restrict__ loglev, float* __restrict__ part, int T)
{
    __shared__ float red[256];
    float s = 0.f;
    for (int i = blockIdx.x * 256 + threadIdx.x; i < T - 2; i += 256 * 128) {
        float d = loglev[i + 2] - 2.f * loglev[i + 1] + loglev[i];
        s = fmaf(d, d, s);
    }
    red[threadIdx.x] = s;
    __syncthreads();
    for (int w = 128; w > 0; w >>= 1) {
        if (threadIdx.x < (unsigned)w) red[threadIdx.x] += red[threadIdx.x + w];
        __syncthreads();
    }
    if (threadIdx.x == 0) part[blockIdx.x] = red[0];
}

__global__ __launch_bounds__(128) void loss2_kernel(
    const float* __restrict__ part, const int* __restrict__ lvp,
    float* __restrict__ out_loss, int T)
{
    __shared__ float red[128];
    red[threadIdx.x] = part[threadIdx.x];
    __syncthreads();
    for (int w = 64; w > 0; w >>= 1) {
        if (threadIdx.x < (unsigned)w) red[threadIdx.x] += red[threadIdx.x + w];
        __syncthreads();
    }
    if (threadIdx.x == 0) out_loss[0] = red[0] * (float)lvp[0] / (float)(T - 2);
}

// ---------------- labels[n,j] = log(x[t]) - log(w[t]) - loglev[n+336], t=n+336+j ----------------
__global__ __launch_bounds__(256) void labels_kernel(
    const float* __restrict__ x, const float* __restrict__ w_all,
    const float* __restrict__ loglev, float* __restrict__ lab, int N)
{
    int idx = blockIdx.x * 256 + threadIdx.x;
    if (idx < N * T_OUT) {
        int n = idx / T_OUT, j = idx - n * T_OUT;
        int t = n + T_WIN + j;
        lab[idx] = __logf(x[t]) - __logf(w_all[t]) - loglev[n + T_WIN];
    }
}

// ---------------- fused MLP: MFMA GEMM1 + fp32 VALU GEMM2, BLOCK-CENTERED bf16 ----------------
// L and ll random-walk to O(10) magnitude (ES neutral-mode drift); quantizing raw L to
// bf16 cost ~0.15 absmax (rounds 2-4). Fix: fold per-block constant C = loglev[n0+336]:
//   pre = sum_j bf16(L[n+j]-C)*bf16(W1[j,c]) + b1[c] - (ll[n]-C)*cs[c]   (exact identity)
__global__ __launch_bounds__(256) void gemm_kernel(
    const float* __restrict__ x, const float* __restrict__ w_all,
    const float* __restrict__ loglev,
    const short* __restrict__ W1T,
    const float* __restrict__ b1, const float* __restrict__ cs,
    const float* __restrict__ W2, const float* __restrict__ b2,
    float* __restrict__ outp, int T, int N)
{
    __shared__ float Lsf[480];
    __shared__ float llv[BM];
    __shared__ float hT[64 * 132];     // h transposed: [c_local][row], 33792 B
    __shared__ float w2s[64 * T_OUT];  // 12288 B

    int tid = threadIdx.x;
    int lane = tid & 63, wv = tid >> 6;
    int lr = lane & 15, lq = lane >> 4;
    int n0 = blockIdx.x * BM;
    int rw = wv * 32;

    float C = loglev[n0 + T_WIN];      // block centering constant (always in-range)

    for (int i = tid; i < 480; i += 256) {
        int t = n0 + i;
        Lsf[i] = (i < 464 && t < T) ? (__logf(x[t]) - __logf(w_all[t]) - C) : 0.f;
    }
    for (int i = tid; i < BM; i += 256) {
        int t = n0 + i + T_WIN;
        llv[i] = (t < T) ? (loglev[t] - C) : 0.f;
    }
    __syncthreads();

    // pack the 22 A-fragments (rows rw..rw+31, K=0..351) into registers
    short8 af[11][2];
    #pragma unroll
    for (int kt = 0; kt < 11; ++kt) {
        #pragma unroll
        for (int mt = 0; mt < 2; ++mt) {
            int E = rw + mt * 16 + lr + kt * 32 + lq * 8;
            union { short8 s; short e[8]; } u;
            #pragma unroll
            for (int j = 0; j < 8; ++j) u.e[j] = f2bf(Lsf[E + j]);
            af[kt][mt] = u.s;
        }
    }

    // fp32 GEMM2 thread mapping
    int m2 = tid & 15, cg2 = tid >> 4;
    int r0 = m2 * 8, o0 = cg2 * 3;
    float acc2[8][3];
    #pragma unroll
    for (int i = 0; i < 8; ++i) { acc2[i][0] = 0.f; acc2[i][1] = 0.f; acc2[i][2] = 0.f; }

    f32x4 zero4 = {0.f, 0.f, 0.f, 0.f};

    for (int c = 0; c < 6; ++c) {
        __syncthreads();   // previous chunk's GEMM2 reads of hT/w2s complete
        // stage this chunk's W2 rows (fp32)
        for (int idx = tid; idx < 64 * T_OUT; idx += 256) {
            int kk = idx / T_OUT, o = idx - kk * T_OUT;
            int krow = c * 64 + kk;
            w2s[idx] = (krow < T_WIN) ? W2[krow * T_OUT + o] : 0.f;
        }
        // per-col fold constants
        float b1v[4], csv[4];
        #pragma unroll
        for (int ct = 0; ct < 4; ++ct) {
            int col = c * 64 + ct * 16 + lr;
            b1v[ct] = (col < T_WIN) ? b1[col] : 0.f;
            csv[ct] = (col < T_WIN) ? cs[col] : 0.f;
        }

        // --- GEMM1: 128x64 tile, K=352 (zero-padded), B-frags straight from W1T ---
        f32x4 acc1[2][4];
        #pragma unroll
        for (int mt = 0; mt < 2; ++mt)
            #pragma unroll
            for (int ct = 0; ct < 4; ++ct) acc1[mt][ct] = zero4;

        #pragma unroll
        for (int kt = 0; kt < 11; ++kt) {
            #pragma unroll
            for (int ct = 0; ct < 4; ++ct) {
                int colg = c * 64 + ct * 16 + lr;          // < 384
                short8 bf = *(const short8*)&W1T[colg * 352 + kt * 32 + lq * 8];
                acc1[0][ct] = __builtin_amdgcn_mfma_f32_16x16x32_bf16(af[kt][0], bf, acc1[0][ct], 0, 0, 0);
                acc1[1][ct] = __builtin_amdgcn_mfma_f32_16x16x32_bf16(af[kt][1], bf, acc1[1][ct], 0, 0, 0);
            }
        }
        // epilogue: fold + tanh -> hT fp32 [c_local][row]
        #pragma unroll
        for (int mt = 0; mt < 2; ++mt)
            #pragma unroll
            for (int ct = 0; ct < 4; ++ct)
                #pragma unroll
                for (int r = 0; r < 4; ++r) {
                    int row = rw + mt * 16 + lq * 4 + r;
                    float pre = acc1[mt][ct][r] + b1v[ct] - llv[row] * csv[ct];
                    float e = __expf(2.f * pre);
                    float h = 1.f - 2.f * __builtin_amdgcn_rcpf(e + 1.f);
                    hT[(ct * 16 + lr) * 132 + row] = h;
                }
        __syncthreads();   // hT + w2s visible

        // --- GEMM2 (fp32 VALU): acc2 += h @ W2chunk ---
        for (int kk = 0; kk < 64; ++kk) {
            float w2v[3];
            #pragma unroll
            for (int oo = 0; oo < 3; ++oo) w2v[oo] = w2s[kk * T_OUT + o0 + oo];
            const float4* hp = (const float4*)&hT[kk * 132 + r0];
            float4 h0 = hp[0], h1 = hp[1];
            float hv[8] = {h0.x, h0.y, h0.z, h0.w, h1.x, h1.y, h1.z, h1.w};
            #pragma unroll
            for (int i = 0; i < 8; ++i)
                #pragma unroll
                for (int oo = 0; oo < 3; ++oo)
                    acc2[i][oo] = fmaf(hv[i], w2v[oo], acc2[i][oo]);
        }
    }

    float bv[3] = {b2[o0], b2[o0 + 1], b2[o0 + 2]};
    #pragma unroll
    for (int i = 0; i < 8; ++i) {
        int n = n0 + r0 + i;
        if (n < N) {
            #pragma unroll
            for (int oo = 0; oo < 3; ++oo)
                outp[(size_t)n * T_OUT + o0 + oo] = acc2[i][oo] + bv[oo];
        }
    }
}

extern "C" void kernel_launch(void* const* d_in, const int* in_sizes, int n_in,
                              void* d_out, int out_size, void* d_ws, size_t ws_size,
                              hipStream_t stream) {
    const float* x    = (const float*)d_in[0];
    const float* lvlc = (const float*)d_in[1];
    const float* seac = (const float*)d_in[2];
    const float* sp   = (const float*)d_in[3];
    const float* W1   = (const float*)d_in[4];
    const float* b1   = (const float*)d_in[5];
    const float* W2   = (const float*)d_in[6];
    const float* b2   = (const float*)d_in[7];
    const int*   lvp  = (const int*)d_in[10];

    int T = in_sizes[0];
    int N = T - T_WIN - T_OUT + 1;

    // ws footprint: 270336 B (W1T) + (3T + 672 + 192) floats ~= 1.47 MB
    short* W1T    = (short*)d_ws;                  // 384*352 shorts, 16B-aligned
    float* w_all  = (float*)(W1T + 384 * 352);     // T + 192
    float* levels = w_all + T + 192;               // T
    float* loglev = levels + T;                    // T
    float* cs     = loglev + T;                    // 352
    float* lpart  = cs + 352;                      // 128

    float* outp  = (float*)d_out;
    float* lab   = outp + (size_t)N * T_OUT;
    float* lossp = lab + (size_t)N * T_OUT;

    prep_w1t<<<264, 256, 0, stream>>>(W1, W1T);
    cs_kernel<<<(T_WIN + 63) / 64, 64, 0, stream>>>(W1, cs);
    scan_kernel<<<1, 64, 0, stream>>>(x, lvlc, seac, sp, w_all, levels, T);
    loglev_kernel<<<(T + 255) / 256, 256, 0, stream>>>(levels, loglev, T);
    loss1_kernel<<<128, 256, 0, stream>>>(loglev, lpart, T);
    loss2_kernel<<<1, 128, 0, stream>>>(lpart, lvp, lossp, T);
    labels_kernel<<<(N * T_OUT + 255) / 256, 256, 0, stream>>>(x, w_all, loglev, lab, N);
    gemm_kernel<<<(N + BM - 1) / BM, 256, 0, stream>>>(x, w_all, loglev, W1T, b1, cs, W2, b2, outp, T, N);
}

// Round 9
// 404.182 us; speedup vs baseline: 2.3540x; 1.1269x over previous
//
#include <hip/hip_runtime.h>
#include <hip/hip_bf16.h>

#define T_WIN 336
#define T_OUT 48
#define T_S   168
#define BM    128

typedef __attribute__((ext_vector_type(8))) short short8;
typedef __attribute__((ext_vector_type(4))) float f32x4;

__device__ __forceinline__ short f2bf(float f) {
    union { float f; unsigned u; } v; v.f = f;
    unsigned r = v.u + 0x7FFFu + ((v.u >> 16) & 1u);
    return (short)(r >> 16);
}

template <int CTRL, int RMASK>
__device__ __forceinline__ float dppf(float v) {
    union { float f; int i; } in, out;
    in.f = v;
    out.i = __builtin_amdgcn_update_dpp(0, in.i, CTRL, RMASK, 0xf, true);
    return out.f;
}

// ---------------- colsum of W1 (fp32) ----------------
__global__ __launch_bounds__(64) void cs_kernel(const float* __restrict__ W1,
                                                float* __restrict__ cs) {
    int k = blockIdx.x * 64 + threadIdx.x;
    if (k < T_WIN) {
        float s = 0.f;
        for (int j = 0; j < T_WIN; ++j) s += W1[j * T_WIN + k];
        cs[k] = s;
    }
}

// ---------------- W1 transpose to bf16: W1T[c][k], K padded to 352, cols to 384 ----------------
__global__ __launch_bounds__(256) void prep_w1t(const float* __restrict__ W1,
                                                short* __restrict__ W1T) {
    int d = blockIdx.x * 256 + threadIdx.x;        // dword index, total 384*176
    int c = d / 176, kp = d % 176, k = 2 * kp;
    unsigned short lo = 0, hi = 0;
    if (c < T_WIN) {
        if (k     < T_WIN) lo = (unsigned short)f2bf(W1[k * T_WIN + c]);
        if (k + 1 < T_WIN) hi = (unsigned short)f2bf(W1[(k + 1) * T_WIN + c]);
    }
    ((unsigned*)W1T)[d] = ((unsigned)hi << 16) | (unsigned)lo;
}

// ---------------- W2 transpose to bf16: W2T[o][k], K padded to 352 (48 rows) ----------------
__global__ __launch_bounds__(256) void prep_w2t(const float* __restrict__ W2,
                                                short* __restrict__ W2T) {
    int d = blockIdx.x * 256 + threadIdx.x;        // dword index, total 48*176
    if (d >= T_OUT * 176) return;
    int o = d / 176, kp = d % 176, k = 2 * kp;
    unsigned short lo = 0, hi = 0;
    if (k     < T_WIN) lo = (unsigned short)f2bf(W2[k * T_OUT + o]);
    if (k + 1 < T_WIN) hi = (unsigned short)f2bf(W2[(k + 1) * T_OUT + o]);
    ((unsigned*)W2T)[d] = ((unsigned)hi << 16) | (unsigned)lo;
}

// ---------------- sequential ES scan, chunk-parallel over the S=168 lag ----------------
// Serial across 596 chunks. __launch_bounds__(64,1) + group-of-4 x prefetch pipeline
// (round-8: 250->~190us; remaining cost is the cross-chunk rcp->DPPx7->readlane chain).
__global__ __launch_bounds__(64, 1) void scan_kernel(
    const float* __restrict__ x, const float* __restrict__ lvl_coef,
    const float* __restrict__ seas_coef, const float* __restrict__ seas_params,
    float* __restrict__ w_all, float* __restrict__ levels, int T)
{
    int lane = threadIdx.x;
    float a = 1.f / (1.f + __expf(-lvl_coef[0]));
    float g = 1.f / (1.f + __expf(-seas_coef[0]));
    float q = 1.f - a, gq = 1.f - g;

    for (int t = lane; t < T_S + 1; t += 64) w_all[t] = __expf(seas_params[t % T_S]);
    float lvl = x[0] / __expf(seas_params[0]);
    if (lane == 0) levels[0] = lvl;

    float wcur[3];
    #pragma unroll
    for (int i = 0; i < 3; ++i)
        wcur[i] = __expf(seas_params[(1 + 3 * lane + i) % T_S]);

    float f1 = q * q * q;
    float f2 = f1 * f1, f4 = f2 * f2, f8 = f4 * f4;
    float lnq = __logf(q);
    float P15 = __expf(3.f * (float)((lane & 15) + 1) * lnq);
    float P31 = __expf(3.f * (float)((lane & 31) + 1) * lnq);
    float pw3l = __expf(3.f * (float)lane * lnq);

    int nch = (T - 1 + T_S - 1) / T_S;  // 596 = 4*149
    int ngrp = (nch + 3) / 4;
    int j0 = 3 * lane;
    bool wr = (lane < 56);

    float xg[4][3], xh[4][3];
    #pragma unroll
    for (int u = 0; u < 4; ++u)
        #pragma unroll
        for (int i = 0; i < 3; ++i)
            xg[u][i] = x[min(1 + T_S * u + j0 + i, T - 1)];

    for (int grp = 0; grp < ngrp; ++grp) {
        #pragma unroll
        for (int u = 0; u < 4; ++u)
            #pragma unroll
            for (int i = 0; i < 3; ++i) {
                int t = 1 + T_S * (4 * (grp + 1) + u) + j0 + i;
                xh[u][i] = x[min(t, T - 1)];
            }

        #pragma unroll
        for (int u = 0; u < 4; ++u) {
            int c = 4 * grp + u;
            int t0 = 1 + T_S * c;
            int len = (T - 1) - T_S * c; if (len > T_S) len = T_S;
            bool full = (len == T_S);

            float rr[3];
            #pragma unroll
            for (int i = 0; i < 3; ++i) rr[i] = a * xg[u][i] * __builtin_amdgcn_rcpf(wcur[i]);
            float S = fmaf(q, fmaf(q, rr[0], rr[1]), rr[2]);
            S = fmaf(f1, dppf<0x111, 0xf>(S), S);   // row_shr:1
            S = fmaf(f2, dppf<0x112, 0xf>(S), S);   // row_shr:2
            S = fmaf(f4, dppf<0x114, 0xf>(S), S);   // row_shr:4
            S = fmaf(f8, dppf<0x118, 0xf>(S), S);   // row_shr:8
            S = fmaf(P15, dppf<0x142, 0xa>(S), S);  // row_bcast:15 -> rows 1,3
            S = fmaf(P31, dppf<0x143, 0xc>(S), S);  // row_bcast:31 -> rows 2,3
            float E = dppf<0x138, 0xf>(S);          // wave_shr:1 (exclusive)

            float lv = fmaf(pw3l, lvl, E);
            float lev[3];
            #pragma unroll
            for (int i = 0; i < 3; ++i) { lv = fmaf(q, lv, rr[i]); lev[i] = lv; }
            { union { float f; int i; } uu; uu.i = __builtin_amdgcn_readlane(__builtin_bit_cast(int, lev[2]), 55); lvl = uu.f; }

            float wn[3];
            #pragma unroll
            for (int i = 0; i < 3; ++i)
                wn[i] = fmaf(gq, wcur[i], g * xg[u][i] * __builtin_amdgcn_rcpf(lev[i]));

            if (full) {
                if (wr) {
                    #pragma unroll
                    for (int i = 0; i < 3; ++i) {
                        levels[t0 + j0 + i] = lev[i];
                        w_all[t0 + j0 + i + T_S] = wn[i];
                    }
                }
            } else {
                #pragma unroll
                for (int i = 0; i < 3; ++i) {
                    if (j0 + i < len) {
                        levels[t0 + j0 + i] = lev[i];
                        w_all[t0 + j0 + i + T_S] = wn[i];
                    }
                }
            }
            #pragma unroll
            for (int i = 0; i < 3; ++i) wcur[i] = wn[i];
        }
        #pragma unroll
        for (int u = 0; u < 4; ++u)
            #pragma unroll
            for (int i = 0; i < 3; ++i) xg[u][i] = xh[u][i];
    }
}

// ---------------- loglev[t] = log(level[t]) ----------------
__global__ __launch_bounds__(256) void loglev_kernel(
    const float* __restrict__ levels, float* __restrict__ loglev, int T)
{
    int t = blockIdx.x * 256 + threadIdx.x;
    if (t < T) loglev[t] = __logf(levels[t]);
}

// ---------------- level variation loss, two-stage ----------------
__global__ __launch_bounds__(256) void loss1_kernel(
    const float* __restrict__ loglev, float* __restrict__ part, int T)
{
    __shared__ float red[256];
    float s = 0.f;
    for (int i = blockIdx.x * 256 + threadIdx.x; i < T - 2; i += 256 * 128) {
        float d = loglev[i + 2] - 2.f * loglev[i + 1] + loglev[i];
        s = fmaf(d, d, s);
    }
    red[threadIdx.x] = s;
    __syncthreads();
    for (int w = 128; w > 0; w >>= 1) {
        if (threadIdx.x < (unsigned)w) red[threadIdx.x] += red[threadIdx.x + w];
        __syncthreads();
    }
    if (threadIdx.x == 0) part[blockIdx.x] = red[0];
}

__global__ __launch_bounds__(128) void loss2_kernel(
    const float* __restrict__ part, const int* __restrict__ lvp,
    float* __restrict__ out_loss, int T)
{
    __shared__ float red[128];
    red[threadIdx.x] = part[threadIdx.x];
    __syncthreads();
    for (int w = 64; w > 0; w >>= 1) {
        if (threadIdx.x < (unsigned)w) red[threadIdx.x] += red[threadIdx.x + w];
        __syncthreads();
    }
    if (threadIdx.x == 0) out_loss[0] = red[0] * (float)lvp[0] / (float)(T - 2);
}

// ---------------- labels[n,j] = log(x[t]) - log(w[t]) - loglev[n+336], t=n+336+j ----------------
__global__ __launch_bounds__(256) void labels_kernel(
    const float* __restrict__ x, const float* __restrict__ w_all,
    const float* __restrict__ loglev, float* __restrict__ lab, int N)
{
    int idx = blockIdx.x * 256 + threadIdx.x;
    if (idx < N * T_OUT) {
        int n = idx / T_OUT, j = idx - n * T_OUT;
        int t = n + T_WIN + j;
        lab[idx] = __logf(x[t]) - __logf(w_all[t]) - loglev[n + T_WIN];
    }
}

// ---------------- fused MLP: MFMA GEMM1 + MFMA GEMM2, BLOCK-CENTERED bf16 ----------------
// Centering (round-5 fix): fold C = loglev[n0+336] so bf16 sees O(1) values:
//   pre = sum_j bf16(L[n+j]-C)*bf16(W1[j,c]) + b1[c] - (ll[n]-C)*cs[c]
// Round-9: GEMM2 fp32 VALU (18.4k cy/wave + stride-132 4-way LDS conflicts) -> MFMA via
// bf16 hs roundtrip (stride-72 shorts = 2-way = free) + natural-layout W2T B-frags.
__global__ __launch_bounds__(256) void gemm_kernel(
    const float* __restrict__ x, const float* __restrict__ w_all,
    const float* __restrict__ loglev,
    const short* __restrict__ W1T, const short* __restrict__ W2T,
    const float* __restrict__ b1, const float* __restrict__ cs,
    const float* __restrict__ b2, float* __restrict__ outp, int T, int N)
{
    __shared__ float Lsf[480];
    __shared__ float llv[BM];
    __shared__ __align__(16) short hs[BM * 72];   // hidden tile bf16, 18432 B

    int tid = threadIdx.x;
    int lane = tid & 63, wv = tid >> 6;
    int lr = lane & 15, lq = lane >> 4;
    int n0 = blockIdx.x * BM;
    int rw = wv * 32;

    float C = loglev[n0 + T_WIN];      // block centering constant

    for (int i = tid; i < 480; i += 256) {
        int t = n0 + i;
        Lsf[i] = (i < 464 && t < T) ? (__logf(x[t]) - __logf(w_all[t]) - C) : 0.f;
    }
    for (int i = tid; i < BM; i += 256) {
        int t = n0 + i + T_WIN;
        llv[i] = (t < T) ? (loglev[t] - C) : 0.f;
    }
    __syncthreads();

    // pack the 22 A-fragments (rows rw..rw+31, K=0..351) into registers
    short8 af[11][2];
    #pragma unroll
    for (int kt = 0; kt < 11; ++kt) {
        #pragma unroll
        for (int mt = 0; mt < 2; ++mt) {
            int E = rw + mt * 16 + lr + kt * 32 + lq * 8;
            union { short8 s; short e[8]; } u;
            #pragma unroll
            for (int j = 0; j < 8; ++j) u.e[j] = f2bf(Lsf[E + j]);
            af[kt][mt] = u.s;
        }
    }

    f32x4 zero4 = {0.f, 0.f, 0.f, 0.f};
    f32x4 acc2[2][3];
    #pragma unroll
    for (int mt = 0; mt < 2; ++mt)
        #pragma unroll
        for (int ct = 0; ct < 3; ++ct) acc2[mt][ct] = zero4;

    for (int c = 0; c < 6; ++c) {
        // per-col fold constants
        float b1v[4], csv[4];
        #pragma unroll
        for (int ct = 0; ct < 4; ++ct) {
            int col = c * 64 + ct * 16 + lr;
            b1v[ct] = (col < T_WIN) ? b1[col] : 0.f;
            csv[ct] = (col < T_WIN) ? cs[col] : 0.f;
        }

        // --- GEMM1: 128x64 tile, K=352 (zero-padded), B-frags from W1T (global/L2) ---
        f32x4 acc1[2][4];
        #pragma unroll
        for (int mt = 0; mt < 2; ++mt)
            #pragma unroll
            for (int ct = 0; ct < 4; ++ct) acc1[mt][ct] = zero4;

        #pragma unroll
        for (int kt = 0; kt < 11; ++kt) {
            #pragma unroll
            for (int ct = 0; ct < 4; ++ct) {
                int colg = c * 64 + ct * 16 + lr;          // < 384
                short8 bf = *(const short8*)&W1T[colg * 352 + kt * 32 + lq * 8];
                acc1[0][ct] = __builtin_amdgcn_mfma_f32_16x16x32_bf16(af[kt][0], bf, acc1[0][ct], 0, 0, 0);
                acc1[1][ct] = __builtin_amdgcn_mfma_f32_16x16x32_bf16(af[kt][1], bf, acc1[1][ct], 0, 0, 0);
            }
        }

        __syncthreads();   // previous chunk's GEMM2 hs-reads complete
        // epilogue: fold + tanh -> hs bf16 [row][c_local], stride 72 shorts
        #pragma unroll
        for (int mt = 0; mt < 2; ++mt)
            #pragma unroll
            for (int ct = 0; ct < 4; ++ct)
                #pragma unroll
                for (int r = 0; r < 4; ++r) {
                    int row = rw + mt * 16 + lq * 4 + r;
                    float pre = acc1[mt][ct][r] + b1v[ct] - llv[row] * csv[ct];
                    float e = __expf(2.f * pre);
                    float h = 1.f - 2.f * __builtin_amdgcn_rcpf(e + 1.f);
                    hs[row * 72 + ct * 16 + lr] = f2bf(h);
                }
        __syncthreads();   // hs visible

        // --- GEMM2 (MFMA): acc2 += h(128x64) @ W2chunk(64x48) ---
        #pragma unroll
        for (int kt2 = 0; kt2 < 2; ++kt2) {
            short8 a2[2];
            #pragma unroll
            for (int mt = 0; mt < 2; ++mt)
                a2[mt] = *(const short8*)&hs[(rw + mt * 16 + lr) * 72 + kt2 * 32 + lq * 8];
            #pragma unroll
            for (int ct2 = 0; ct2 < 3; ++ct2) {
                short8 bf2 = *(const short8*)&W2T[(ct2 * 16 + lr) * 352 + c * 64 + kt2 * 32 + lq * 8];
                acc2[0][ct2] = __builtin_amdgcn_mfma_f32_16x16x32_bf16(a2[0], bf2, acc2[0][ct2], 0, 0, 0);
                acc2[1][ct2] = __builtin_amdgcn_mfma_f32_16x16x32_bf16(a2[1], bf2, acc2[1][ct2], 0, 0, 0);
            }
        }
    }

    float b2v[3];
    #pragma unroll
    for (int ct2 = 0; ct2 < 3; ++ct2) b2v[ct2] = b2[ct2 * 16 + lr];
    #pragma unroll
    for (int mt = 0; mt < 2; ++mt)
        #pragma unroll
        for (int ct2 = 0; ct2 < 3; ++ct2)
            #pragma unroll
            for (int r = 0; r < 4; ++r) {
                int row = n0 + rw + mt * 16 + lq * 4 + r;
                if (row < N)
                    outp[(size_t)row * T_OUT + ct2 * 16 + lr] = acc2[mt][ct2][r] + b2v[ct2];
            }
}

extern "C" void kernel_launch(void* const* d_in, const int* in_sizes, int n_in,
                              void* d_out, int out_size, void* d_ws, size_t ws_size,
                              hipStream_t stream) {
    const float* x    = (const float*)d_in[0];
    const float* lvlc = (const float*)d_in[1];
    const float* seac = (const float*)d_in[2];
    const float* sp   = (const float*)d_in[3];
    const float* W1   = (const float*)d_in[4];
    const float* b1   = (const float*)d_in[5];
    const float* W2   = (const float*)d_in[6];
    const float* b2   = (const float*)d_in[7];
    const int*   lvp  = (const int*)d_in[10];

    int T = in_sizes[0];
    int N = T - T_WIN - T_OUT + 1;

    // ws: W1T 270336 B + W2T 33792 B + (3T + 672 + 192) floats ~= 1.51 MB (< proven 1.61)
    short* W1T    = (short*)d_ws;                  // 384*352 shorts
    short* W2T    = W1T + 384 * 352;               // 48*352 shorts
    float* w_all  = (float*)(W2T + 48 * 352);      // T + 192
    float* levels = w_all + T + 192;               // T
    float* loglev = levels + T;                    // T
    float* cs     = loglev + T;                    // 352
    float* lpart  = cs + 352;                      // 128

    float* outp  = (float*)d_out;
    float* lab   = outp + (size_t)N * T_OUT;
    float* lossp = lab + (size_t)N * T_OUT;

    prep_w1t<<<264, 256, 0, stream>>>(W1, W1T);
    prep_w2t<<<33, 256, 0, stream>>>(W2, W2T);
    cs_kernel<<<(T_WIN + 63) / 64, 64, 0, stream>>>(W1, cs);
    scan_kernel<<<1, 64, 0, stream>>>(x, lvlc, seac, sp, w_all, levels, T);
    loglev_kernel<<<(T + 255) / 256, 256, 0, stream>>>(levels, loglev, T);
    loss1_kernel<<<128, 256, 0, stream>>>(loglev, lpart, T);
    loss2_kernel<<<1, 128, 0, stream>>>(lpart, lvp, lossp, T);
    labels_kernel<<<(N * T_OUT + 255) / 256, 256, 0, stream>>>(x, w_all, loglev, lab, N);
    gemm_kernel<<<(N + BM - 1) / BM, 256, 0, stream>>>(x, w_all, loglev, W1T, W2T, b1, cs, b2, outp, T, N);
}

// Round 10
// 375.960 us; speedup vs baseline: 2.5307x; 1.0751x over previous
//
#include <hip/hip_runtime.h>
#include <hip/hip_bf16.h>

#define T_WIN 336
#define T_OUT 48
#define T_S   168
#define BM    128
#define CH    782   // ceil(100000/128) for fused loglev+loss

typedef __attribute__((ext_vector_type(8))) short short8;
typedef __attribute__((ext_vector_type(4))) float f32x4;

__device__ __forceinline__ short f2bf(float f) {
    union { float f; unsigned u; } v; v.f = f;
    unsigned r = v.u + 0x7FFFu + ((v.u >> 16) & 1u);
    return (short)(r >> 16);
}

template <int CTRL, int RMASK>
__device__ __forceinline__ float dppf(float v) {
    union { float f; int i; } in, out;
    in.f = v;
    out.i = __builtin_amdgcn_update_dpp(0, in.i, CTRL, RMASK, 0xf, true);
    return out.f;
}

// ---------------- colsum of W1 (fp32) ----------------
__global__ __launch_bounds__(64) void cs_kernel(const float* __restrict__ W1,
                                                float* __restrict__ cs) {
    int k = blockIdx.x * 64 + threadIdx.x;
    if (k < T_WIN) {
        float s = 0.f;
        for (int j = 0; j < T_WIN; ++j) s += W1[j * T_WIN + k];
        cs[k] = s;
    }
}

// ---------------- W1 -> MFMA B-fragment order: [f=(c*11+kt)*4+ct][lane][j0..7] ----------------
// Element: W1[k][col], k = kt*32 + (lane>>4)*8 + j, col = c*64 + ct*16 + (lane&15).
// gemm loads &W1F[f*512 + lane*8]: consecutive lanes -> consecutive 16B (coalesced 1KB).
__global__ __launch_bounds__(256) void prep_w1f(const float* __restrict__ W1,
                                                short* __restrict__ W1F) {
    int d = blockIdx.x * 256 + threadIdx.x;   // dword idx, total 264*256 = 67584
    int j2 = d & 3, lane = (d >> 2) & 63, f = d >> 8;      // f < 264
    int ct = f & 3, rest = f >> 2;
    int kt = rest % 11, c = rest / 11;
    int k = kt * 32 + (lane >> 4) * 8 + 2 * j2;
    int col = c * 64 + ct * 16 + (lane & 15);
    unsigned short lo = 0, hi = 0;
    if (col < T_WIN) {
        if (k     < T_WIN) lo = (unsigned short)f2bf(W1[k * T_WIN + col]);
        if (k + 1 < T_WIN) hi = (unsigned short)f2bf(W1[(k + 1) * T_WIN + col]);
    }
    ((unsigned*)W1F)[d] = ((unsigned)hi << 16) | (unsigned)lo;
}

// ---------------- W2 -> MFMA B-fragment order: [f=(c*2+kt2)*3+ct2][lane][j] ----------------
// Element: W2[k][o], k = c*64 + kt2*32 + (lane>>4)*8 + j, o = ct2*16 + (lane&15).
__global__ __launch_bounds__(256) void prep_w2f(const float* __restrict__ W2,
                                                short* __restrict__ W2F) {
    int d = blockIdx.x * 256 + threadIdx.x;   // dword idx, total 36*256 = 9216
    int j2 = d & 3, lane = (d >> 2) & 63, f = d >> 8;      // f < 36
    int ct2 = f % 3, rest = f / 3;
    int kt2 = rest & 1, c = rest >> 1;
    int k = c * 64 + kt2 * 32 + (lane >> 4) * 8 + 2 * j2;
    int o = ct2 * 16 + (lane & 15);
    unsigned short lo = 0, hi = 0;
    if (k     < T_WIN) lo = (unsigned short)f2bf(W2[k * T_OUT + o]);
    if (k + 1 < T_WIN) hi = (unsigned short)f2bf(W2[(k + 1) * T_OUT + o]);
    ((unsigned*)W2F)[d] = ((unsigned)hi << 16) | (unsigned)lo;
}

// ---------------- sequential ES scan ----------------
// Serial across 596 chunks (lag S=168 = 1 chunk). DPP affine scan; group-of-4 x prefetch;
// round-10 diet: base-pointer + immediate-offset addressing, unclamped fast-path prefetch.
__global__ __launch_bounds__(64, 1) void scan_kernel(
    const float* __restrict__ x, const float* __restrict__ lvl_coef,
    const float* __restrict__ seas_coef, const float* __restrict__ seas_params,
    float* __restrict__ w_all, float* __restrict__ levels, int T)
{
    int lane = threadIdx.x;
    float a = 1.f / (1.f + __expf(-lvl_coef[0]));
    float g = 1.f / (1.f + __expf(-seas_coef[0]));
    float q = 1.f - a, gq = 1.f - g;

    for (int t = lane; t < T_S + 1; t += 64) w_all[t] = __expf(seas_params[t % T_S]);
    float lvl = x[0] / __expf(seas_params[0]);
    if (lane == 0) levels[0] = lvl;

    float wcur[3];
    #pragma unroll
    for (int i = 0; i < 3; ++i)
        wcur[i] = __expf(seas_params[(1 + 3 * lane + i) % T_S]);

    float f1 = q * q * q;
    float f2 = f1 * f1, f4 = f2 * f2, f8 = f4 * f4;
    float lnq = __logf(q);
    float P15 = __expf(3.f * (float)((lane & 15) + 1) * lnq);
    float P31 = __expf(3.f * (float)((lane & 31) + 1) * lnq);
    float pw3l = __expf(3.f * (float)lane * lnq);

    int nch = (T - 1 + T_S - 1) / T_S;  // 596
    int ngrp = (nch + 3) / 4;           // 149
    int j0 = 3 * lane;
    bool wr = (lane < 56);

    float xg[4][3], xh[4][3];
    #pragma unroll
    for (int u = 0; u < 4; ++u)
        #pragma unroll
        for (int i = 0; i < 3; ++i)
            xg[u][i] = x[min(1 + T_S * u + j0 + i, T - 1)];

    const float* px = x + 1 + 4 * T_S + j0;   // prefetch base for group grp+1 (at grp=0)
    float* pl = levels + 1 + j0;
    float* pw = w_all + 1 + T_S + j0;

    for (int grp = 0; grp < ngrp; ++grp) {
        // prefetch next group's 12 x values
        if (grp <= ngrp - 3) {            // all prefetched chunks full: unclamped
            #pragma unroll
            for (int u = 0; u < 4; ++u)
                #pragma unroll
                for (int i = 0; i < 3; ++i)
                    xh[u][i] = px[u * T_S + i];
        } else {                           // tail groups: clamped
            #pragma unroll
            for (int u = 0; u < 4; ++u)
                #pragma unroll
                for (int i = 0; i < 3; ++i) {
                    int t = 1 + T_S * (4 * (grp + 1) + u) + j0 + i;
                    xh[u][i] = x[min(t, T - 1)];
                }
        }
        px += 4 * T_S;

        #pragma unroll
        for (int u = 0; u < 4; ++u) {
            int c = 4 * grp + u;
            if (c >= nch) break;
            int len = (T - 1) - T_S * c; if (len > T_S) len = T_S;
            bool full = (len == T_S);

            float rr[3];
            #pragma unroll
            for (int i = 0; i < 3; ++i) rr[i] = a * xg[u][i] * __builtin_amdgcn_rcpf(wcur[i]);
            float S = fmaf(q, fmaf(q, rr[0], rr[1]), rr[2]);
            S = fmaf(f1, dppf<0x111, 0xf>(S), S);   // row_shr:1
            S = fmaf(f2, dppf<0x112, 0xf>(S), S);   // row_shr:2
            S = fmaf(f4, dppf<0x114, 0xf>(S), S);   // row_shr:4
            S = fmaf(f8, dppf<0x118, 0xf>(S), S);   // row_shr:8
            S = fmaf(P15, dppf<0x142, 0xa>(S), S);  // row_bcast:15 -> rows 1,3
            S = fmaf(P31, dppf<0x143, 0xc>(S), S);  // row_bcast:31 -> rows 2,3
            float E = dppf<0x138, 0xf>(S);          // wave_shr:1 (exclusive)

            float lv = fmaf(pw3l, lvl, E);
            float lev[3];
            #pragma unroll
            for (int i = 0; i < 3; ++i) { lv = fmaf(q, lv, rr[i]); lev[i] = lv; }
            { union { float f; int i; } uu; uu.i = __builtin_amdgcn_readlane(__builtin_bit_cast(int, lev[2]), 55); lvl = uu.f; }

            float wn[3];
            #pragma unroll
            for (int i = 0; i < 3; ++i)
                wn[i] = fmaf(gq, wcur[i], g * xg[u][i] * __builtin_amdgcn_rcpf(lev[i]));

            if (full) {
                if (wr) {
                    #pragma unroll
                    for (int i = 0; i < 3; ++i) { pl[i] = lev[i]; pw[i] = wn[i]; }
                }
            } else {
                #pragma unroll
                for (int i = 0; i < 3; ++i)
                    if (j0 + i < len) { pl[i] = lev[i]; pw[i] = wn[i]; }
            }
            pl += T_S; pw += T_S;
            #pragma unroll
            for (int i = 0; i < 3; ++i) wcur[i] = wn[i];
        }
        #pragma unroll
        for (int u = 0; u < 4; ++u)
            #pragma unroll
            for (int i = 0; i < 3; ++i) xg[u][i] = xh[u][i];
    }
}

// ---------------- fused: loglev[t]=log(levels[t]) + level-variation-loss partials ----------------
__global__ __launch_bounds__(256) void loglev_loss_kernel(
    const float* __restrict__ levels, float* __restrict__ loglev,
    float* __restrict__ part, int T)
{
    __shared__ float ls[CH + 2];
    __shared__ float red[256];
    int lo = blockIdx.x * CH;
    int n = T - lo; if (n > CH + 2) n = CH + 2;
    for (int i = threadIdx.x; i < n; i += 256) ls[i] = __logf(levels[lo + i]);
    __syncthreads();
    int m = T - lo; if (m > CH) m = CH;
    for (int i = threadIdx.x; i < m; i += 256) loglev[lo + i] = ls[i];
    float s = 0.f;
    int dmax = (T - 2) - lo; if (dmax > CH) dmax = CH;
    for (int i = threadIdx.x; i < dmax; i += 256) {
        float d = ls[i + 2] - 2.f * ls[i + 1] + ls[i];
        s = fmaf(d, d, s);
    }
    red[threadIdx.x] = s;
    __syncthreads();
    for (int w = 128; w > 0; w >>= 1) {
        if (threadIdx.x < (unsigned)w) red[threadIdx.x] += red[threadIdx.x + w];
        __syncthreads();
    }
    if (threadIdx.x == 0) part[blockIdx.x] = red[0];
}

__global__ __launch_bounds__(128) void loss2_kernel(
    const float* __restrict__ part, const int* __restrict__ lvp,
    float* __restrict__ out_loss, int T)
{
    __shared__ float red[128];
    red[threadIdx.x] = part[threadIdx.x];
    __syncthreads();
    for (int w = 64; w > 0; w >>= 1) {
        if (threadIdx.x < (unsigned)w) red[threadIdx.x] += red[threadIdx.x + w];
        __syncthreads();
    }
    if (threadIdx.x == 0) out_loss[0] = red[0] * (float)lvp[0] / (float)(T - 2);
}

// ---------------- fused MLP (MFMA GEMM1+GEMM2, block-centered bf16) + labels ----------------
// pre = sum_j bf16(L[n+j]-C)*bf16(W1[j,c]) + b1[c] - (ll[n]-C)*cs[c]; h=tanh; out=h@W2+b2
// labels[n,j] = (L[n+336+j]-C) - (ll[n]-C)  (exact).  B-frags from pre-swizzled W1F/W2F:
// lane-contiguous 16B -> coalesced (round-9's 704B-stride gather was the 169us bottleneck).
__global__ __launch_bounds__(256) void gemm_kernel(
    const float* __restrict__ x, const float* __restrict__ w_all,
    const float* __restrict__ loglev,
    const short* __restrict__ W1F, const short* __restrict__ W2F,
    const float* __restrict__ b1, const float* __restrict__ cs,
    const float* __restrict__ b2, float* __restrict__ outp,
    float* __restrict__ lab, int T, int N)
{
    __shared__ float Lsf[512];
    __shared__ float llv[BM];
    __shared__ __align__(16) short hs[BM * 72];   // hidden tile bf16, 18432 B

    int tid = threadIdx.x;
    int lane = tid & 63, wv = tid >> 6;
    int lr = lane & 15, lq = lane >> 4;
    int n0 = blockIdx.x * BM;
    int rw = wv * 32;

    float C = loglev[n0 + T_WIN];      // block centering constant

    for (int i = tid; i < 512; i += 256) {
        int t = n0 + i;
        Lsf[i] = (t < T) ? (__logf(x[t]) - __logf(w_all[t]) - C) : 0.f;
    }
    for (int i = tid; i < BM; i += 256) {
        int t = n0 + i + T_WIN;
        llv[i] = (t < T) ? (loglev[t] - C) : 0.f;
    }
    __syncthreads();

    // fused labels: lab[n][j] = Lsf[row+336+j] - llv[row]
    for (int u2 = tid; u2 < BM * T_OUT; u2 += 256) {
        int row = u2 / T_OUT, j = u2 - row * T_OUT;
        int n = n0 + row;
        if (n < N) lab[(size_t)n * T_OUT + j] = Lsf[row + T_WIN + j] - llv[row];
    }

    // pack the 22 A-fragments (rows rw..rw+31, K=0..351) into registers
    short8 af[11][2];
    #pragma unroll
    for (int kt = 0; kt < 11; ++kt) {
        #pragma unroll
        for (int mt = 0; mt < 2; ++mt) {
            int E = rw + mt * 16 + lr + kt * 32 + lq * 8;
            union { short8 s; short e[8]; } u;
            #pragma unroll
            for (int j = 0; j < 8; ++j) u.e[j] = f2bf(Lsf[E + j]);
            af[kt][mt] = u.s;
        }
    }

    f32x4 zero4 = {0.f, 0.f, 0.f, 0.f};
    f32x4 acc2[2][3];
    #pragma unroll
    for (int mt = 0; mt < 2; ++mt)
        #pragma unroll
        for (int ct = 0; ct < 3; ++ct) acc2[mt][ct] = zero4;

    for (int c = 0; c < 6; ++c) {
        float b1v[4], csv[4];
        #pragma unroll
        for (int ct = 0; ct < 4; ++ct) {
            int col = c * 64 + ct * 16 + lr;
            b1v[ct] = (col < T_WIN) ? b1[col] : 0.f;
            csv[ct] = (col < T_WIN) ? cs[col] : 0.f;
        }

        // --- GEMM1: 128x64 tile, K=352; B-frags coalesced from W1F ---
        f32x4 acc1[2][4];
        #pragma unroll
        for (int mt = 0; mt < 2; ++mt)
            #pragma unroll
            for (int ct = 0; ct < 4; ++ct) acc1[mt][ct] = zero4;

        const short* Wc1 = W1F + (size_t)c * 11 * 4 * 512;
        #pragma unroll
        for (int kt = 0; kt < 11; ++kt) {
            #pragma unroll
            for (int ct = 0; ct < 4; ++ct) {
                short8 bf = *(const short8*)&Wc1[((kt * 4 + ct) * 64 + lane) * 8];
                acc1[0][ct] = __builtin_amdgcn_mfma_f32_16x16x32_bf16(af[kt][0], bf, acc1[0][ct], 0, 0, 0);
                acc1[1][ct] = __builtin_amdgcn_mfma_f32_16x16x32_bf16(af[kt][1], bf, acc1[1][ct], 0, 0, 0);
            }
        }

        __syncthreads();   // previous chunk's GEMM2 hs-reads complete
        #pragma unroll
        for (int mt = 0; mt < 2; ++mt)
            #pragma unroll
            for (int ct = 0; ct < 4; ++ct)
                #pragma unroll
                for (int r = 0; r < 4; ++r) {
                    int row = rw + mt * 16 + lq * 4 + r;
                    float pre = acc1[mt][ct][r] + b1v[ct] - llv[row] * csv[ct];
                    float e = __expf(2.f * pre);
                    float h = 1.f - 2.f * __builtin_amdgcn_rcpf(e + 1.f);
                    hs[row * 72 + ct * 16 + lr] = f2bf(h);
                }
        __syncthreads();   // hs visible

        // --- GEMM2 (MFMA): acc2 += h(128x64) @ W2chunk(64x48), B-frags coalesced ---
        #pragma unroll
        for (int kt2 = 0; kt2 < 2; ++kt2) {
            short8 a2[2];
            #pragma unroll
            for (int mt = 0; mt < 2; ++mt)
                a2[mt] = *(const short8*)&hs[(rw + mt * 16 + lr) * 72 + kt2 * 32 + lq * 8];
            #pragma unroll
            for (int ct2 = 0; ct2 < 3; ++ct2) {
                short8 bf2 = *(const short8*)&W2F[(((c * 2 + kt2) * 3 + ct2) * 64 + lane) * 8];
                acc2[0][ct2] = __builtin_amdgcn_mfma_f32_16x16x32_bf16(a2[0], bf2, acc2[0][ct2], 0, 0, 0);
                acc2[1][ct2] = __builtin_amdgcn_mfma_f32_16x16x32_bf16(a2[1], bf2, acc2[1][ct2], 0, 0, 0);
            }
        }
    }

    float b2v[3];
    #pragma unroll
    for (int ct2 = 0; ct2 < 3; ++ct2) b2v[ct2] = b2[ct2 * 16 + lr];
    #pragma unroll
    for (int mt = 0; mt < 2; ++mt)
        #pragma unroll
        for (int ct2 = 0; ct2 < 3; ++ct2)
            #pragma unroll
            for (int r = 0; r < 4; ++r) {
                int row = n0 + rw + mt * 16 + lq * 4 + r;
                if (row < N)
                    outp[(size_t)row * T_OUT + ct2 * 16 + lr] = acc2[mt][ct2][r] + b2v[ct2];
            }
}

extern "C" void kernel_launch(void* const* d_in, const int* in_sizes, int n_in,
                              void* d_out, int out_size, void* d_ws, size_t ws_size,
                              hipStream_t stream) {
    const float* x    = (const float*)d_in[0];
    const float* lvlc = (const float*)d_in[1];
    const float* seac = (const float*)d_in[2];
    const float* sp   = (const float*)d_in[3];
    const float* W1   = (const float*)d_in[4];
    const float* b1   = (const float*)d_in[5];
    const float* W2   = (const float*)d_in[6];
    const float* b2   = (const float*)d_in[7];
    const int*   lvp  = (const int*)d_in[10];

    int T = in_sizes[0];
    int N = T - T_WIN - T_OUT + 1;

    // ws: W1F 264KB + W2F 36KB + (3T + 480 + 192) floats ~= 1.51 MB (< proven 1.61)
    short* W1F    = (short*)d_ws;                  // 264*512 shorts
    short* W2F    = W1F + 264 * 512;               // 36*512 shorts
    float* w_all  = (float*)(W2F + 36 * 512);      // T + 192
    float* levels = w_all + T + 192;               // T
    float* loglev = levels + T;                    // T
    float* cs     = loglev + T;                    // 352
    float* lpart  = cs + 352;                      // 128

    float* outp  = (float*)d_out;
    float* lab   = outp + (size_t)N * T_OUT;
    float* lossp = lab + (size_t)N * T_OUT;

    prep_w1f<<<264, 256, 0, stream>>>(W1, W1F);
    prep_w2f<<<36, 256, 0, stream>>>(W2, W2F);
    cs_kernel<<<(T_WIN + 63) / 64, 64, 0, stream>>>(W1, cs);
    scan_kernel<<<1, 64, 0, stream>>>(x, lvlc, seac, sp, w_all, levels, T);
    loglev_loss_kernel<<<128, 256, 0, stream>>>(levels, loglev, lpart, T);
    loss2_kernel<<<1, 128, 0, stream>>>(lpart, lvp, lossp, T);
    gemm_kernel<<<(N + BM - 1) / BM, 256, 0, stream>>>(x, w_all, loglev, W1F, W2F, b1, cs, b2, outp, lab, T, N);
}

// Round 11
// 360.041 us; speedup vs baseline: 2.6426x; 1.0442x over previous
//
#include <hip/hip_runtime.h>
#include <hip/hip_bf16.h>

#define T_WIN 336
#define T_OUT 48
#define T_S   168
#define BM    128
#define CH    782

typedef __attribute__((ext_vector_type(8))) short short8;
typedef __attribute__((ext_vector_type(4))) float f32x4;

__device__ __forceinline__ short f2bf(float f) {
    union { float f; unsigned u; } v; v.f = f;
    unsigned r = v.u + 0x7FFFu + ((v.u >> 16) & 1u);
    return (short)(r >> 16);
}

template <int CTRL, int RMASK>
__device__ __forceinline__ float dppf(float v) {
    union { float f; int i; } in, out;
    in.f = v;
    out.i = __builtin_amdgcn_update_dpp(0, in.i, CTRL, RMASK, 0xf, true);
    return out.f;
}

// =============== fused: scan (block 0) + W1F/W2F prep + cs (blocks 1..302) ===============
// Block 0: serial ES scan, one wave, DPP affine scan (sync-free => safe in 256-thr block).
// Blocks 1..264: W1->MFMA-B-frag bf16 swizzle. 265..300: W2 swizzle. 301..302: colsum(W1).
__global__ __launch_bounds__(256, 1) void prep_scan_kernel(
    const float* __restrict__ x, const float* __restrict__ lvl_coef,
    const float* __restrict__ seas_coef, const float* __restrict__ seas_params,
    const float* __restrict__ W1, const float* __restrict__ W2,
    float* __restrict__ w_all, float* __restrict__ levels,
    short* __restrict__ W1F, short* __restrict__ W2F,
    float* __restrict__ cs, int T)
{
    int blk = blockIdx.x;
    int tid = threadIdx.x;

    if (blk >= 301) {              // ---- cs: colsum of W1 ----
        int k = (blk - 301) * 256 + tid;
        if (k < T_WIN) {
            float s = 0.f;
            for (int j = 0; j < T_WIN; ++j) s += W1[j * T_WIN + k];
            cs[k] = s;
        }
        return;
    }
    if (blk >= 265) {              // ---- prep W2F: [f=(c*2+kt2)*3+ct2][lane][j] ----
        int d = (blk - 265) * 256 + tid;          // < 9216
        int j2 = d & 3, lane = (d >> 2) & 63, f = d >> 8;
        int ct2 = f % 3, rest = f / 3;
        int kt2 = rest & 1, c = rest >> 1;
        int k = c * 64 + kt2 * 32 + (lane >> 4) * 8 + 2 * j2;
        int o = ct2 * 16 + (lane & 15);
        unsigned short lo = 0, hi = 0;
        if (k     < T_WIN) lo = (unsigned short)f2bf(W2[k * T_OUT + o]);
        if (k + 1 < T_WIN) hi = (unsigned short)f2bf(W2[(k + 1) * T_OUT + o]);
        ((unsigned*)W2F)[d] = ((unsigned)hi << 16) | (unsigned)lo;
        return;
    }
    if (blk >= 1) {                // ---- prep W1F: [f=(c*11+kt)*4+ct][lane][j] ----
        int d = (blk - 1) * 256 + tid;            // < 67584
        int j2 = d & 3, lane = (d >> 2) & 63, f = d >> 8;
        int ct = f & 3, rest = f >> 2;
        int kt = rest % 11, c = rest / 11;
        int k = kt * 32 + (lane >> 4) * 8 + 2 * j2;
        int col = c * 64 + ct * 16 + (lane & 15);
        unsigned short lo = 0, hi = 0;
        if (col < T_WIN) {
            if (k     < T_WIN) lo = (unsigned short)f2bf(W1[k * T_WIN + col]);
            if (k + 1 < T_WIN) hi = (unsigned short)f2bf(W1[(k + 1) * T_WIN + col]);
        }
        ((unsigned*)W1F)[d] = ((unsigned)hi << 16) | (unsigned)lo;
        return;
    }

    // ---- block 0: the scan (threads 64..255 exit; one wave, no block syncs) ----
    if (tid >= 64) return;
    int lane = tid;
    float a = 1.f / (1.f + __expf(-lvl_coef[0]));
    float g = 1.f / (1.f + __expf(-seas_coef[0]));
    float q = 1.f - a, gq = 1.f - g;

    for (int t = lane; t < T_S + 1; t += 64) w_all[t] = __expf(seas_params[t % T_S]);
    float lvl = x[0] / __expf(seas_params[0]);
    if (lane == 0) levels[0] = lvl;

    float wcur[3];
    #pragma unroll
    for (int i = 0; i < 3; ++i)
        wcur[i] = __expf(seas_params[(1 + 3 * lane + i) % T_S]);

    float f1 = q * q * q;
    float f2 = f1 * f1, f4 = f2 * f2, f8 = f4 * f4;
    float lnq = __logf(q);
    float P15 = __expf(3.f * (float)((lane & 15) + 1) * lnq);
    float P31 = __expf(3.f * (float)((lane & 31) + 1) * lnq);
    float pw3l = __expf(3.f * (float)lane * lnq);

    int nch = (T - 1 + T_S - 1) / T_S;  // 596
    int ngrp = (nch + 3) / 4;           // 149
    int j0 = 3 * lane;
    bool wr = (lane < 56);

    // depth-2 group prefetch pipeline (12 loads/group, ~2 groups ≈ 1800cy in flight)
    float xg[4][3], xh[4][3], x2[4][3];
    #pragma unroll
    for (int u = 0; u < 4; ++u)
        #pragma unroll
        for (int i = 0; i < 3; ++i) {
            xg[u][i] = x[min(1 + T_S * u + j0 + i, T - 1)];
            xh[u][i] = x[min(1 + T_S * (4 + u) + j0 + i, T - 1)];
        }

    float* pl = levels + 1 + j0;
    float* pw = w_all + 1 + T_S + j0;

    for (int grp = 0; grp < ngrp; ++grp) {
        #pragma unroll
        for (int u = 0; u < 4; ++u)
            #pragma unroll
            for (int i = 0; i < 3; ++i) {
                int t = 1 + T_S * (4 * (grp + 2) + u) + j0 + i;
                x2[u][i] = x[min(t, T - 1)];
            }

        #pragma unroll
        for (int u = 0; u < 4; ++u) {
            int c = 4 * grp + u;
            if (c >= nch) break;
            int len = (T - 1) - T_S * c; if (len > T_S) len = T_S;
            bool full = (len == T_S);

            float rr[3];
            #pragma unroll
            for (int i = 0; i < 3; ++i) rr[i] = a * xg[u][i] * __builtin_amdgcn_rcpf(wcur[i]);
            float S = fmaf(q, fmaf(q, rr[0], rr[1]), rr[2]);
            S = fmaf(f1, dppf<0x111, 0xf>(S), S);   // row_shr:1
            S = fmaf(f2, dppf<0x112, 0xf>(S), S);   // row_shr:2
            S = fmaf(f4, dppf<0x114, 0xf>(S), S);   // row_shr:4
            S = fmaf(f8, dppf<0x118, 0xf>(S), S);   // row_shr:8
            S = fmaf(P15, dppf<0x142, 0xa>(S), S);  // row_bcast:15 -> rows 1,3
            S = fmaf(P31, dppf<0x143, 0xc>(S), S);  // row_bcast:31 -> rows 2,3
            float E = dppf<0x138, 0xf>(S);          // wave_shr:1 (exclusive)

            float lv = fmaf(pw3l, lvl, E);
            float lev[3];
            #pragma unroll
            for (int i = 0; i < 3; ++i) { lv = fmaf(q, lv, rr[i]); lev[i] = lv; }
            { union { float f; int i; } uu; uu.i = __builtin_amdgcn_readlane(__builtin_bit_cast(int, lev[2]), 55); lvl = uu.f; }

            float wn[3];
            #pragma unroll
            for (int i = 0; i < 3; ++i)
                wn[i] = fmaf(gq, wcur[i], g * xg[u][i] * __builtin_amdgcn_rcpf(lev[i]));

            if (full) {
                if (wr) {
                    #pragma unroll
                    for (int i = 0; i < 3; ++i) { pl[i] = lev[i]; pw[i] = wn[i]; }
                }
            } else {
                #pragma unroll
                for (int i = 0; i < 3; ++i)
                    if (j0 + i < len) { pl[i] = lev[i]; pw[i] = wn[i]; }
            }
            pl += T_S; pw += T_S;
            #pragma unroll
            for (int i = 0; i < 3; ++i) wcur[i] = wn[i];
        }
        #pragma unroll
        for (int u = 0; u < 4; ++u)
            #pragma unroll
            for (int i = 0; i < 3; ++i) { xg[u][i] = xh[u][i]; xh[u][i] = x2[u][i]; }
    }
}

// ---------------- level-variation loss from levels (logs inline), two-stage ----------------
__global__ __launch_bounds__(256) void loss1_kernel(
    const float* __restrict__ levels, float* __restrict__ part, int T)
{
    __shared__ float ls[CH + 2];
    __shared__ float red[256];
    int lo = blockIdx.x * CH;
    int n = T - lo; if (n > CH + 2) n = CH + 2;
    for (int i = threadIdx.x; i < n; i += 256) ls[i] = __logf(levels[lo + i]);
    __syncthreads();
    float s = 0.f;
    int dmax = (T - 2) - lo; if (dmax > CH) dmax = CH;
    for (int i = threadIdx.x; i < dmax; i += 256) {
        float d = ls[i + 2] - 2.f * ls[i + 1] + ls[i];
        s = fmaf(d, d, s);
    }
    red[threadIdx.x] = s;
    __syncthreads();
    for (int w = 128; w > 0; w >>= 1) {
        if (threadIdx.x < (unsigned)w) red[threadIdx.x] += red[threadIdx.x + w];
        __syncthreads();
    }
    if (threadIdx.x == 0) part[blockIdx.x] = red[0];
}

__global__ __launch_bounds__(128) void loss2_kernel(
    const float* __restrict__ part, const int* __restrict__ lvp,
    float* __restrict__ out_loss, int T)
{
    __shared__ float red[128];
    red[threadIdx.x] = part[threadIdx.x];
    __syncthreads();
    for (int w = 64; w > 0; w >>= 1) {
        if (threadIdx.x < (unsigned)w) red[threadIdx.x] += red[threadIdx.x + w];
        __syncthreads();
    }
    if (threadIdx.x == 0) out_loss[0] = red[0] * (float)lvp[0] / (float)(T - 2);
}

// ---------------- fused MLP (MFMA GEMM1+GEMM2) + labels, BARRIER-FREE chunk loop ----------------
// Wave-local hs roundtrip: wave wv's GEMM1 epilogue writes exactly rows rw..rw+31, and its
// GEMM2 A-frags read exactly rows rw..rw+31 -> no inter-wave dependency, no __syncthreads
// in the chunk loop (round-10's 12 barriers/block were the latency bound).
// A-frags via parity bf16 LDS copies (Lbf1[i]=Lbf0[i+1]): 4-aligned b32 reads, no scalar pack.
__global__ __launch_bounds__(256) void gemm_kernel(
    const float* __restrict__ x, const float* __restrict__ w_all,
    const float* __restrict__ levels,
    const short* __restrict__ W1F, const short* __restrict__ W2F,
    const float* __restrict__ b1, const float* __restrict__ cs,
    const float* __restrict__ b2, float* __restrict__ outp,
    float* __restrict__ lab, int T, int N)
{
    __shared__ float Lsf[512];
    __shared__ __align__(16) short Lbf0[512];
    __shared__ __align__(16) short Lbf1[512];
    __shared__ float llv[BM];
    __shared__ __align__(16) short hs[BM * 72];

    int tid = threadIdx.x;
    int lane = tid & 63, wv = tid >> 6;
    int lr = lane & 15, lq = lane >> 4;
    int n0 = blockIdx.x * BM;
    int rw = wv * 32;

    float C = __logf(levels[min(n0 + T_WIN, T - 1)]);   // block centering constant

    for (int i = tid; i < 512; i += 256) {
        int t = n0 + i;
        float v = (t < T) ? (__logf(x[t]) - __logf(w_all[t]) - C) : 0.f;
        Lsf[i] = v;
        Lbf0[i] = f2bf(v);
    }
    for (int i = tid; i < BM; i += 256) {
        int t = n0 + i + T_WIN;
        llv[i] = (t < T) ? (__logf(levels[t]) - C) : 0.f;
    }
    __syncthreads();
    for (int i = tid; i < 512; i += 256) Lbf1[i] = (i < 511) ? Lbf0[i + 1] : (short)0;
    __syncthreads();

    // fused labels: lab[n][j] = Lsf[row+336+j] - llv[row]
    for (int u2 = tid; u2 < BM * T_OUT; u2 += 256) {
        int row = u2 / T_OUT, j = u2 - row * T_OUT;
        int n = n0 + row;
        if (n < N) lab[(size_t)n * T_OUT + j] = Lsf[row + T_WIN + j] - llv[row];
    }

    // pack 22 A-fragments from parity arrays: E = rw + mt*16 + lr + kt*32 + lq*8
    // parity(E) = lr&1 (rest even) -> per-lane constant array select, 4B-aligned reads
    const short* abase = ((lr & 1) ? Lbf1 : Lbf0) + rw + (lr & ~1);
    short8 af[11][2];
    #pragma unroll
    for (int kt = 0; kt < 11; ++kt) {
        #pragma unroll
        for (int mt = 0; mt < 2; ++mt) {
            const int* ip = (const int*)(abase + mt * 16 + kt * 32 + lq * 8);
            union { short8 s; int i[4]; } u;
            u.i[0] = ip[0]; u.i[1] = ip[1]; u.i[2] = ip[2]; u.i[3] = ip[3];
            af[kt][mt] = u.s;
        }
    }

    f32x4 zero4 = {0.f, 0.f, 0.f, 0.f};
    f32x4 acc2[2][3];
    #pragma unroll
    for (int mt = 0; mt < 2; ++mt)
        #pragma unroll
        for (int ct = 0; ct < 3; ++ct) acc2[mt][ct] = zero4;

    for (int c = 0; c < 6; ++c) {
        float b1v[4], csv[4];
        #pragma unroll
        for (int ct = 0; ct < 4; ++ct) {
            int col = c * 64 + ct * 16 + lr;
            b1v[ct] = (col < T_WIN) ? b1[col] : 0.f;
            csv[ct] = (col < T_WIN) ? cs[col] : 0.f;
        }

        // --- GEMM1: 128x64 tile, K=352; coalesced B-frags from W1F ---
        f32x4 acc1[2][4];
        #pragma unroll
        for (int mt = 0; mt < 2; ++mt)
            #pragma unroll
            for (int ct = 0; ct < 4; ++ct) acc1[mt][ct] = zero4;

        const short* Wc1 = W1F + (size_t)c * 11 * 4 * 512;
        #pragma unroll
        for (int kt = 0; kt < 11; ++kt) {
            #pragma unroll
            for (int ct = 0; ct < 4; ++ct) {
                short8 bf = *(const short8*)&Wc1[((kt * 4 + ct) * 64 + lane) * 8];
                acc1[0][ct] = __builtin_amdgcn_mfma_f32_16x16x32_bf16(af[kt][0], bf, acc1[0][ct], 0, 0, 0);
                acc1[1][ct] = __builtin_amdgcn_mfma_f32_16x16x32_bf16(af[kt][1], bf, acc1[1][ct], 0, 0, 0);
            }
        }

        // epilogue: fold + tanh -> hs (bf16), rows rw..rw+31 = THIS wave's rows (no barrier)
        #pragma unroll
        for (int mt = 0; mt < 2; ++mt)
            #pragma unroll
            for (int ct = 0; ct < 4; ++ct)
                #pragma unroll
                for (int r = 0; r < 4; ++r) {
                    int row = rw + mt * 16 + lq * 4 + r;
                    float pre = acc1[mt][ct][r] + b1v[ct] - llv[row] * csv[ct];
                    float e = __expf(2.f * pre);
                    float h = 1.f - 2.f * __builtin_amdgcn_rcpf(e + 1.f);
                    hs[row * 72 + ct * 16 + lr] = f2bf(h);
                }

        // --- GEMM2 (MFMA): same wave reads back its own rows (no barrier) ---
        #pragma unroll
        for (int kt2 = 0; kt2 < 2; ++kt2) {
            short8 a2[2];
            #pragma unroll
            for (int mt = 0; mt < 2; ++mt)
                a2[mt] = *(const short8*)&hs[(rw + mt * 16 + lr) * 72 + kt2 * 32 + lq * 8];
            #pragma unroll
            for (int ct2 = 0; ct2 < 3; ++ct2) {
                short8 bf2 = *(const short8*)&W2F[(((c * 2 + kt2) * 3 + ct2) * 64 + lane) * 8];
                acc2[0][ct2] = __builtin_amdgcn_mfma_f32_16x16x32_bf16(a2[0], bf2, acc2[0][ct2], 0, 0, 0);
                acc2[1][ct2] = __builtin_amdgcn_mfma_f32_16x16x32_bf16(a2[1], bf2, acc2[1][ct2], 0, 0, 0);
            }
        }
    }

    float b2v[3];
    #pragma unroll
    for (int ct2 = 0; ct2 < 3; ++ct2) b2v[ct2] = b2[ct2 * 16 + lr];
    #pragma unroll
    for (int mt = 0; mt < 2; ++mt)
        #pragma unroll
        for (int ct2 = 0; ct2 < 3; ++ct2)
            #pragma unroll
            for (int r = 0; r < 4; ++r) {
                int row = n0 + rw + mt * 16 + lq * 4 + r;
                if (row < N)
                    outp[(size_t)row * T_OUT + ct2 * 16 + lr] = acc2[mt][ct2][r] + b2v[ct2];
            }
}

extern "C" void kernel_launch(void* const* d_in, const int* in_sizes, int n_in,
                              void* d_out, int out_size, void* d_ws, size_t ws_size,
                              hipStream_t stream) {
    const float* x    = (const float*)d_in[0];
    const float* lvlc = (const float*)d_in[1];
    const float* seac = (const float*)d_in[2];
    const float* sp   = (const float*)d_in[3];
    const float* W1   = (const float*)d_in[4];
    const float* b1   = (const float*)d_in[5];
    const float* W2   = (const float*)d_in[6];
    const float* b2   = (const float*)d_in[7];
    const int*   lvp  = (const int*)d_in[10];

    int T = in_sizes[0];
    int N = T - T_WIN - T_OUT + 1;

    // ws: W1F 264KB + W2F 36KB + (2T + 672) floats ~= 1.11 MB (< proven 1.51)
    short* W1F    = (short*)d_ws;                  // 264*512 shorts
    short* W2F    = W1F + 264 * 512;               // 36*512 shorts
    float* w_all  = (float*)(W2F + 36 * 512);      // T + 192
    float* levels = w_all + T + 192;               // T
    float* cs     = levels + T;                    // 352
    float* lpart  = cs + 352;                      // 128

    float* outp  = (float*)d_out;
    float* lab   = outp + (size_t)N * T_OUT;
    float* lossp = lab + (size_t)N * T_OUT;

    prep_scan_kernel<<<303, 256, 0, stream>>>(x, lvlc, seac, sp, W1, W2,
                                              w_all, levels, W1F, W2F, cs, T);
    gemm_kernel<<<(N + BM - 1) / BM, 256, 0, stream>>>(x, w_all, levels, W1F, W2F,
                                                       b1, cs, b2, outp, lab, T, N);
    loss1_kernel<<<128, 256, 0, stream>>>(levels, lpart, T);
    loss2_kernel<<<1, 128, 0, stream>>>(lpart, lvp, lossp, T);
}